// Round 6
// baseline (883.630 us; speedup 1.0000x reference)
//
#include <hip/hip_runtime.h>
#include <hip/hip_bf16.h>
#include <math.h>

#define DIM 896
#define DD  (DIM * DIM)
#define NH 8
#define HD 112
#define BB 64
#define TT 8
#define KA 65
#define KAPAD 4224   // 64*65 = 4160 padded to 33*128
#define KT 512
#define NKEYS (TT + KA + KT)   // 585

#define EPI_NONE  0
#define EPI_ROPE  1
#define EPI_RESID 2
#define EPI_RELU  3

// -log2(10000)/56
#define NEG_L2_10K_OVER_56 (-0.2373327285062406f)

#ifndef __has_builtin
#define __has_builtin(x) 0
#endif
#if __has_builtin(__builtin_amdgcn_global_load_lds)
#define HAS_GLL 1
#else
#define HAS_GLL 0
#endif

typedef __attribute__((ext_vector_type(8))) short bf16x8_t;   // 8 bf16 (4 VGPRs)
typedef __attribute__((ext_vector_type(4))) float f32x4_t;    // MFMA accumulator

__device__ __forceinline__ short f2bf(float f) {
  unsigned u = __float_as_uint(f);
  u += 0x7fffu + ((u >> 16) & 1u);
  return (short)(u >> 16);
}
__device__ __forceinline__ float bf2f(short s) {
  return __uint_as_float(((unsigned)(unsigned short)s) << 16);
}
// 2x f32 -> packed bf16 pair (RNE; bit-identical to f2bf for normals).
__device__ __forceinline__ unsigned cvt_pk_bf16(float lo, float hi) {
  unsigned r;
  asm("v_cvt_pk_bf16_f32 %0, %1, %2" : "=v"(r) : "v"(lo), "v"(hi));
  return r;
}
// 16-B global -> LDS direct copy. dest = lbase + lane*16B (wave-uniform base).
__device__ __forceinline__ void gll16(const short* g, short* lbase, int lane) {
#if HAS_GLL
  __builtin_amdgcn_global_load_lds(
      (const __attribute__((address_space(1))) unsigned*)g,
      (__attribute__((address_space(3))) unsigned*)lbase, 16, 0, 0);
#else
  *(bf16x8_t*)(lbase + lane * 8) = *(const bf16x8_t*)g;
#endif
}

// ---------------- 9-way weight transpose: W[k][n] f32 -> Wt[n][k] bf16 ----------------
struct W9 { const float* w[9]; };

__global__ __launch_bounds__(256) void wtrans(W9 ws, short* __restrict__ Wt)
{
  __shared__ float t[32][33];
  const float* W = ws.w[blockIdx.z];
  short* dst = Wt + (size_t)blockIdx.z * DD;
  const int bx = blockIdx.x, by = blockIdx.y;
  const int tx = threadIdx.x & 31, ty = threadIdx.x >> 5;
#pragma unroll
  for (int i = 0; i < 4; ++i)
    t[ty + i * 8][tx] = W[(size_t)(by * 32 + ty + i * 8) * DIM + bx * 32 + tx];
  __syncthreads();
#pragma unroll
  for (int i = 0; i < 4; ++i)
    dst[(size_t)(bx * 32 + ty + i * 8) * DIM + by * 32 + tx] = f2bf(t[tx][ty + i * 8]);
}

// ---------------- h_ad = concat(h_a, p) -> bf16, zero-padded to 4224 rows ----------------
__global__ __launch_bounds__(256) void build_had(
    const float* __restrict__ h_a, const float* __restrict__ p,
    short* __restrict__ had)
{
  const int i = blockIdx.x * 256 + threadIdx.x;  // one per 8 elements
  const int total = KAPAD * DIM / 8;
  if (i >= total) return;
  const int c = (i % 112) * 8;
  const int row = i / 112;
  bf16x8_t o;
  if (row >= BB * KA) {
#pragma unroll
    for (int j = 0; j < 8; ++j) o[j] = 0;
  } else {
    const int b = row / KA, j = row % KA;
    const float* src = (j < KA - 1) ? h_a + ((size_t)b * (KA - 1) + j) * DIM + c
                                    : p + (size_t)b * DIM + c;
    const float4 a = *(const float4*)src;
    const float4 d = *(const float4*)(src + 4);
    o[0] = f2bf(a.x); o[1] = f2bf(a.y); o[2] = f2bf(a.z); o[3] = f2bf(a.w);
    o[4] = f2bf(d.x); o[5] = f2bf(d.y); o[6] = f2bf(d.z); o[7] = f2bf(d.w);
  }
  ((bf16x8_t*)had)[i] = o;
}

// ---------------- MFMA GEMM, double-buffered K-loop (T3 "minimum 2-phase") ---------
// C[M x N] = A[M x 896](bf16 or f32) @ Wt[N x 896](bf16, n-major) + bias.
// 128x128 tile, BK=32, 4 waves x (4x4 of 16x16x32). Per K-step: issue next tile's
// loads into buffer Y, compute current from buffer X, (AF32: cvt+write late), ONE
// barrier. The vmcnt drain at the barrier overlaps the 16 MFMAs instead of
// serializing after staging (m233's 72% stall).
// swz: bijective XCD remap (gridDim.y % 8 == 0) — A panels fetched by one L2 each.
// hm[sub] != 0 => head-major bf16 store (see earlier rounds).
struct EpiCfg {
  const float* bias[3];
  float* outF[3];
  short* outB[3];
  const float* resid;
  int epi[3];
  int pos_mod[3];
  int row_off;     // global row offset
  int hm[3];       // head-major store flag
  int hm_L[3];     // rows per batch (grow decode)
  int hm_ltot[3];  // row stride per (b,h) in the destination
  int swz;         // XCD swizzle on/off
};

template <bool AF32>
__global__ __launch_bounds__(256) void gemm_bf16(
    const short* __restrict__ A, const float* __restrict__ Af,
    const short* __restrict__ Wt, EpiCfg cfg)
{
  __shared__ __align__(16) short AsA[128 * 32];  // [m][k] 64 B rows, buffer A
  __shared__ __align__(16) short AsB[128 * 32];  // buffer B
  __shared__ __align__(16) short BsA[128 * 32];  // [n][k]
  __shared__ __align__(16) short BsB[128 * 32];
  const int tid = threadIdx.x;
  const int wave = tid >> 6, lane = tid & 63;

  int bx = blockIdx.x, by = blockIdx.y;
  if (cfg.swz) {
    const int nx = gridDim.x;
    const int bid = blockIdx.x + blockIdx.y * nx;   // HW dispatch order
    const int xcd = bid & 7, ixd = bid >> 3;
    const int rpx = gridDim.y >> 3;                 // row panels per XCD
    bx = ixd % nx;
    by = xcd * rpx + ixd / nx;
  }
  const int sub = bx / 7;
  const int col0 = (bx % 7) * 128;      // within sub
  const int row0 = by * 128;
  const int wm = wave >> 1, wn = wave & 1;
  const int lm = lane & 15, lq = lane >> 4;

  // staging source: lane -> row-in-16 = lane>>2, k-octet = (lane&3)*8
  const int sm = lane >> 2, sk = (lane & 3) * 8;
  const short* Ag0 = A + (size_t)(row0 + wave * 32 + sm) * DIM + sk;
  const short* Ag1 = Ag0 + (size_t)16 * DIM;
  const short* Wg0 = Wt + (size_t)(sub * DIM + col0 + wave * 32 + sm) * DIM + sk;
  const short* Wg1 = Wg0 + (size_t)16 * DIM;

  // AF32 staging: thread tid owns rows am and am+64, k-octet ako (16 B chunks).
  const int am = tid >> 2, ako = (tid & 3) * 8;
  const float* af0 = nullptr;
  const float* af1 = nullptr;
  if constexpr (AF32) {
    af0 = Af + (size_t)(row0 + am) * DIM + ako;
    af1 = af0 + (size_t)64 * DIM;
  }

  f32x4_t acc[4][4];
#pragma unroll
  for (int i = 0; i < 4; ++i)
#pragma unroll
    for (int j = 0; j < 4; ++j) acc[i][j] = (f32x4_t){0.f, 0.f, 0.f, 0.f};

  // ---- prologue: stage k=0 into buffers A ----
  if constexpr (AF32) {
    const float4 p0a = *(const float4*)(af0);
    const float4 p0b = *(const float4*)(af0 + 4);
    const float4 p1a = *(const float4*)(af1);
    const float4 p1b = *(const float4*)(af1 + 4);
    uint4 w;
    w.x = cvt_pk_bf16(p0a.x, p0a.y); w.y = cvt_pk_bf16(p0a.z, p0a.w);
    w.z = cvt_pk_bf16(p0b.x, p0b.y); w.w = cvt_pk_bf16(p0b.z, p0b.w);
    *(uint4*)&AsA[tid * 8] = w;
    w.x = cvt_pk_bf16(p1a.x, p1a.y); w.y = cvt_pk_bf16(p1a.z, p1a.w);
    w.z = cvt_pk_bf16(p1b.x, p1b.y); w.w = cvt_pk_bf16(p1b.z, p1b.w);
    *(uint4*)&AsA[(tid + 256) * 8] = w;
  } else {
    gll16(Ag0, &AsA[(wave * 32) * 32], lane);
    gll16(Ag1, &AsA[(wave * 32 + 16) * 32], lane);
  }
  gll16(Wg0, &BsA[(wave * 32) * 32], lane);
  gll16(Wg1, &BsA[(wave * 32 + 16) * 32], lane);
  __syncthreads();

  // phase: compute from (AsX,BsX) while staging k=kn into (AsY,BsY)
#define GEMM_PHASE(AsX, BsX, AsY, BsY, kn, doStage)                            \
  {                                                                            \
    float4 n0a, n0b, n1a, n1b;                                                 \
    if (doStage) {                                                             \
      if constexpr (AF32) {                                                    \
        n0a = *(const float4*)(af0 + (kn));                                    \
        n0b = *(const float4*)(af0 + (kn) + 4);                                \
        n1a = *(const float4*)(af1 + (kn));                                    \
        n1b = *(const float4*)(af1 + (kn) + 4);                                \
      } else {                                                                 \
        gll16(Ag0 + (kn), &AsY[(wave * 32) * 32], lane);                       \
        gll16(Ag1 + (kn), &AsY[(wave * 32 + 16) * 32], lane);                  \
      }                                                                        \
      gll16(Wg0 + (kn), &BsY[(wave * 32) * 32], lane);                         \
      gll16(Wg1 + (kn), &BsY[(wave * 32 + 16) * 32], lane);                    \
    }                                                                          \
    bf16x8_t afr[4], bfr[4];                                                   \
    _Pragma("unroll")                                                          \
    for (int t = 0; t < 4; ++t)                                                \
      afr[t] = *(const bf16x8_t*)&AsX[(wm * 64 + t * 16 + lm) * 32 + lq * 8];  \
    _Pragma("unroll")                                                          \
    for (int t = 0; t < 4; ++t)                                                \
      bfr[t] = *(const bf16x8_t*)&BsX[(wn * 64 + t * 16 + lm) * 32 + lq * 8];  \
    _Pragma("unroll")                                                          \
    for (int tm = 0; tm < 4; ++tm)                                             \
      _Pragma("unroll")                                                        \
      for (int tn = 0; tn < 4; ++tn)                                           \
        acc[tm][tn] = __builtin_amdgcn_mfma_f32_16x16x32_bf16(                 \
            afr[tm], bfr[tn], acc[tm][tn], 0, 0, 0);                           \
    if constexpr (AF32) {                                                      \
      if (doStage) {                                                           \
        uint4 w;                                                               \
        w.x = cvt_pk_bf16(n0a.x, n0a.y); w.y = cvt_pk_bf16(n0a.z, n0a.w);      \
        w.z = cvt_pk_bf16(n0b.x, n0b.y); w.w = cvt_pk_bf16(n0b.z, n0b.w);      \
        *(uint4*)&AsY[tid * 8] = w;                                            \
        w.x = cvt_pk_bf16(n1a.x, n1a.y); w.y = cvt_pk_bf16(n1a.z, n1a.w);      \
        w.z = cvt_pk_bf16(n1b.x, n1b.y); w.w = cvt_pk_bf16(n1b.z, n1b.w);      \
        *(uint4*)&AsY[(tid + 256) * 8] = w;                                    \
      }                                                                        \
    }                                                                          \
    __syncthreads();                                                           \
  }

  // 28 K-steps = 14 x (phase A, phase B); buffers alternate statically.
  for (int k0 = 0; k0 < DIM; k0 += 64) {
    GEMM_PHASE(AsA, BsA, AsB, BsB, k0 + 32, true);
    GEMM_PHASE(AsB, BsB, AsA, BsA, k0 + 64, (k0 + 64) < DIM);
  }
#undef GEMM_PHASE

  // epilogue — C/D frag: row = lq*4 + reg, col = lm (per 16x16 tile)
  const float* bias = cfg.bias[sub];
  float* outF = cfg.outF[sub];
  short* outB = cfg.outB[sub];
  const int epi = cfg.epi[sub], pm = cfg.pos_mod[sub];
  const int hm = cfg.hm[sub];
  const int L = cfg.hm_L[sub], ltot = cfg.hm_ltot[sub];
  int gb[4][4], gl[4][4];
  if (hm) {
#pragma unroll
    for (int tm = 0; tm < 4; ++tm) {
      const int g = cfg.row_off + row0 + wm * 64 + tm * 16 + lq * 4;
      int bq2 = g / L;
      int l = g - bq2 * L;
#pragma unroll
      for (int r = 0; r < 4; ++r) {
        gb[tm][r] = bq2; gl[tm][r] = l;
        if (++l == L) { l = 0; ++bq2; }
      }
    }
  }
#pragma unroll
  for (int tn = 0; tn < 4; ++tn) {
    const int col = col0 + wn * 64 + tn * 16 + lm;
    const float bv = bias[col];
    int hcol = 0, dcol = 0;
    if (hm) { hcol = col / HD; dcol = col - hcol * HD; }
    float fr = 0.f, sgn = 0.f;
    if (epi == EPI_ROPE) {
      const int d0 = col % HD;
      fr = exp2f((float)(d0 % 56) * NEG_L2_10K_OVER_56);
      sgn = (d0 & 1) ? 1.f : -1.f;
    }
#pragma unroll
    for (int tm = 0; tm < 4; ++tm) {
#pragma unroll
      for (int r = 0; r < 4; ++r) {
        const int grow = cfg.row_off + row0 + wm * 64 + tm * 16 + lq * 4 + r;
        float v = acc[tm][tn][r] + bv;
        if (epi == EPI_ROPE) {
          const float prt = __shfl_xor(v, 1);  // partner col (lane^1), pre-rope
          const int pos = hm ? gl[tm][r] : (grow % pm);
          float s, c;
          __sincosf((float)pos * fr, &s, &c);
          v = v * c + sgn * prt * s;
        } else if (epi == EPI_RESID) {
          v += cfg.resid[(size_t)grow * DIM + col];
        } else if (epi == EPI_RELU) {
          v = fmaxf(v, 0.f);
        }
        if (hm) {
          if (gb[tm][r] < BB)
            outB[((size_t)(gb[tm][r] * NH + hcol) * ltot + gl[tm][r]) * HD + dcol] =
                f2bf(v);
        } else if (outB) {
          outB[(size_t)grow * DIM + col] = f2bf(v);
        } else {
          outF[(size_t)grow * DIM + col] = v;
        }
      }
    }
  }
}

// ---------------- attention: one 1024-thread block per (b,h) (round-1 proven) -------
// Inputs head-major: q [b][h][8][112]; kall/vall [b][h][585][112] with key
// segments s(0..7) | a(8..72) | t(73..584). Output row-major [b*8+t][DIM].
#define SCP 10   // score row stride (floats): conflict-free (gcd(10,32)=2), float2-aligned

__global__ __launch_bounds__(1024, 8) void attn_kernel(
    const short* __restrict__ q, const short* __restrict__ kall,
    const short* __restrict__ vall, const float* __restrict__ gate,
    short* __restrict__ out)
{
  __shared__ __align__(16) float qs[TT * HD];        // 3584 B
  __shared__ __align__(16) float sc[NKEYS * SCP];    // 23400 B, [k][t] padded
  __shared__ float red[TT * TT * HD];                // 28672 B, [g][t][d]
  __shared__ float isum[TT];
  const int tid = threadIdx.x;
  const int bh = blockIdx.x;
  const float scale = 0.09449111825230681f;  // 1/sqrt(112)
  const float rg = tanhf(gate[0]);

  // phase 0: q -> fp32 LDS (contiguous head-major load)
  if (tid < TT * HD) qs[tid] = bf2f(q[(size_t)bh * (TT * HD) + tid]);
  __syncthreads();

  // phase 1: scores — one thread per key, contiguous 224 B key row
  if (tid < NKEYS) {
    const int k = tid;
    const short* kp = kall + ((size_t)bh * NKEYS + k) * HD;
    float dot[TT] = {};
    for (int d8 = 0; d8 < HD; d8 += 8) {
      const bf16x8_t kv8 = *(const bf16x8_t*)(kp + d8);
      float kf[8];
#pragma unroll
      for (int j = 0; j < 8; ++j) kf[j] = bf2f(kv8[j]);
#pragma unroll
      for (int t = 0; t < TT; ++t) {
        const float4 qa = *(const float4*)&qs[t * HD + d8];
        const float4 qb4 = *(const float4*)&qs[t * HD + d8 + 4];
        dot[t] = fmaf(qa.x, kf[0], dot[t]);
        dot[t] = fmaf(qa.y, kf[1], dot[t]);
        dot[t] = fmaf(qa.z, kf[2], dot[t]);
        dot[t] = fmaf(qa.w, kf[3], dot[t]);
        dot[t] = fmaf(qb4.x, kf[4], dot[t]);
        dot[t] = fmaf(qb4.y, kf[5], dot[t]);
        dot[t] = fmaf(qb4.z, kf[6], dot[t]);
        dot[t] = fmaf(qb4.w, kf[7], dot[t]);
      }
    }
    const float s = (k >= TT + KA) ? scale * rg : scale;
#pragma unroll
    for (int t = 0; t < TT; ++t) sc[k * SCP + t] = dot[t] * s;
  }
  __syncthreads();

  // phase 2: softmax per t-row, one wave per row
  const int wave = tid >> 6, lane = tid & 63;
  if (wave < TT) {
    const int t = wave;
    float m = -1e30f;
    for (int k = lane; k < NKEYS; k += 64) m = fmaxf(m, sc[k * SCP + t]);
#pragma unroll
    for (int o = 32; o >= 1; o >>= 1) m = fmaxf(m, __shfl_xor(m, o));
    float sum = 0.f;
    for (int k = lane; k < NKEYS; k += 64) {
      const float e = expf(sc[k * SCP + t] - m);
      sc[k * SCP + t] = e;
      sum += e;
    }
#pragma unroll
    for (int o = 32; o >= 1; o >>= 1) sum += __shfl_xor(sum, o);
    if (lane == 0) isum[t] = 1.f / sum;
  }
  __syncthreads();

  // phase 3: PV partials — keys split 8 ways, each thread owns (group g, dim d),
  // accumulates all 8 t's; v read from HBM exactly once, coalesced over d.
  if (tid < TT * HD) {
    const int g = tid / HD, d = tid - (tid / HD) * HD;
    const int kb = (g * NKEYS) / TT, ke = ((g + 1) * NKEYS) / TT;
    const short* vp = vall + (size_t)bh * (NKEYS * HD) + d;
    float acc[TT] = {};
    for (int k = kb; k < ke; ++k) {
      const float vv = bf2f(vp[(size_t)k * HD]);
      const float2 s0 = *(const float2*)&sc[k * SCP];
      const float2 s1 = *(const float2*)&sc[k * SCP + 2];
      const float2 s2 = *(const float2*)&sc[k * SCP + 4];
      const float2 s3 = *(const float2*)&sc[k * SCP + 6];
      acc[0] = fmaf(s0.x, vv, acc[0]);
      acc[1] = fmaf(s0.y, vv, acc[1]);
      acc[2] = fmaf(s1.x, vv, acc[2]);
      acc[3] = fmaf(s1.y, vv, acc[3]);
      acc[4] = fmaf(s2.x, vv, acc[4]);
      acc[5] = fmaf(s2.y, vv, acc[5]);
      acc[6] = fmaf(s3.x, vv, acc[6]);
      acc[7] = fmaf(s3.y, vv, acc[7]);
    }
#pragma unroll
    for (int t = 0; t < TT; ++t) red[(g * TT + t) * HD + d] = acc[t];
  }
  __syncthreads();

  // phase 4: cross-group reduce + normalize + store (row-major for out-proj)
  if (tid < TT * HD) {
    const int t = tid / HD, d = tid - (tid / HD) * HD;
    float a = 0.f;
#pragma unroll
    for (int g = 0; g < TT; ++g) a += red[(g * TT + t) * HD + d];
    out[((size_t)(bh >> 3) * TT + t) * DIM + (bh & 7) * HD + d] = f2bf(a * isum[t]);
  }
}

// ---------------- layernorm: fp32 in -> bf16 out ----------------
__global__ __launch_bounds__(256) void ln_kernel(
    const float* __restrict__ y, const float* __restrict__ g,
    const float* __restrict__ beta, short* __restrict__ yn)
{
  __shared__ float s1[4], s2[4];
  const int r = blockIdx.x, tid = threadIdx.x;
  const float* row = y + (size_t)r * DIM;
  float sum = 0.f, sq = 0.f;
  for (int c = tid; c < DIM; c += 256) {
    const float v = row[c];
    sum += v;
    sq = fmaf(v, v, sq);
  }
#pragma unroll
  for (int o = 32; o >= 1; o >>= 1) {
    sum += __shfl_xor(sum, o);
    sq  += __shfl_xor(sq, o);
  }
  const int wave = tid >> 6, lane = tid & 63;
  if (lane == 0) { s1[wave] = sum; s2[wave] = sq; }
  __syncthreads();
  sum = s1[0] + s1[1] + s1[2] + s1[3];
  sq  = s2[0] + s2[1] + s2[2] + s2[3];
  const float mu = sum / DIM;
  const float var = sq / DIM - mu * mu;
  const float rstd = 1.f / sqrtf(var + 1e-5f);
  for (int c = tid; c < DIM; c += 256)
    yn[(size_t)r * DIM + c] = f2bf((row[c] - mu) * rstd * g[c] + beta[c]);
}

// ---------------- launch ----------------
extern "C" void kernel_launch(void* const* d_in, const int* in_sizes, int n_in,
                              void* d_out, int out_size, void* d_ws, size_t ws_size,
                              hipStream_t stream)
{
  const float* x   = (const float*)d_in[0];
  const float* h_a = (const float*)d_in[1];
  const float* h_t = (const float*)d_in[2];
  const float* p   = (const float*)d_in[3];
  const float* Wq  = (const float*)d_in[4];  const float* bq  = (const float*)d_in[5];
  const float* Wks = (const float*)d_in[6];  const float* bks = (const float*)d_in[7];
  const float* Wvs = (const float*)d_in[8];  const float* bvs = (const float*)d_in[9];
  const float* Wka = (const float*)d_in[10]; const float* bka = (const float*)d_in[11];
  const float* Wva = (const float*)d_in[12]; const float* bva = (const float*)d_in[13];
  const float* Wkt = (const float*)d_in[14]; const float* bkt = (const float*)d_in[15];
  const float* Wvt = (const float*)d_in[16]; const float* bvt = (const float*)d_in[17];
  const float* Wo  = (const float*)d_in[18]; const float* bo  = (const float*)d_in[19];
  const float* Wf  = (const float*)d_in[20]; const float* bf_ = (const float*)d_in[21];
  const float* gate = (const float*)d_in[22];
  const float* ln_g = (const float*)d_in[23];
  const float* ln_b = (const float*)d_in[24];

  // ---- workspace layout (bytes). Total = 160.8 MB < proven 167.67 MB ----
  const size_t SZ_HAD = (size_t)KAPAD * DIM * 2;            // bf16
  const size_t SZ_SM  = (size_t)BB * TT * DIM * 2;          // bf16 small [512 x 896]
  const size_t SZ_KV  = (size_t)BB * NH * NKEYS * HD * 2;   // bf16 [b][h][585][112]
  const size_t SZ_WT  = (size_t)9 * DD * 2;                 // 9 weights bf16
  const size_t needed = SZ_HAD + SZ_SM * 3 + SZ_KV * 2 + SZ_WT
                        + (size_t)BB * TT * DIM * 4;        // + yb fp32
  if (ws_size < needed) return;  // fail loud, not UB

  char* wsp = (char*)d_ws;
  short* hadb = (short*)wsp; wsp += SZ_HAD;
  short* qb   = (short*)wsp; wsp += SZ_SM;   // head-major [b][h][8][112]
  short* kall = (short*)wsp; wsp += SZ_KV;   // head-major [b][h][585][112]
  short* vall = (short*)wsp; wsp += SZ_KV;
  short* WtA  = (short*)wsp; wsp += SZ_WT;
  short* attn_outb = (short*)wsp; wsp += SZ_SM;
  float* yb   = (float*)wsp; wsp += (size_t)BB * TT * DIM * 4;
  short* ynb  = (short*)wsp; wsp += SZ_SM;

  dim3 blk(256);

  // 0) transpose all 9 weights -> bf16 [n][k], concatenated
  W9 w9; const float* Ws[9] = {Wq, Wks, Wvs, Wka, Wva, Wkt, Wvt, Wo, Wf};
  for (int i = 0; i < 9; ++i) w9.w[i] = Ws[i];
  wtrans<<<dim3(28, 28, 9), blk, 0, stream>>>(w9, WtA);

  // 1) h_ad -> bf16 (concat gather needs its own pass)
  build_had<<<(KAPAD * DIM / 8 + 255) / 256, blk, 0, stream>>>(h_a, p, hadb);

  // 2) fused S-group GEMM: [q | k_s | v_s] = x(f32) @ [Wq|Wks|Wvs] (head-major out)
  {
    EpiCfg c = {};
    c.bias[0] = bq;  c.outB[0] = qb;   c.epi[0] = EPI_ROPE; c.pos_mod[0] = TT;
    c.hm[0] = 1; c.hm_L[0] = TT; c.hm_ltot[0] = TT;
    c.bias[1] = bks; c.outB[1] = kall; c.epi[1] = EPI_ROPE; c.pos_mod[1] = TT;
    c.hm[1] = 1; c.hm_L[1] = TT; c.hm_ltot[1] = NKEYS;
    c.bias[2] = bvs; c.outB[2] = vall; c.epi[2] = EPI_NONE; c.pos_mod[2] = 1;
    c.hm[2] = 1; c.hm_L[2] = TT; c.hm_ltot[2] = NKEYS;
    gemm_bf16<true><<<dim3(21, BB * TT / 128), blk, 0, stream>>>(nullptr, x, WtA, c);
  }
  // 3) fused A-group GEMM: [k_a | v_a] = hadb @ [Wka|Wva] (head-major, seg off 8)
  {
    EpiCfg c = {};
    c.bias[0] = bka; c.outB[0] = kall + (size_t)TT * HD; c.epi[0] = EPI_ROPE;
    c.pos_mod[0] = KA; c.hm[0] = 1; c.hm_L[0] = KA; c.hm_ltot[0] = NKEYS;
    c.bias[1] = bva; c.outB[1] = vall + (size_t)TT * HD; c.epi[1] = EPI_NONE;
    c.pos_mod[1] = 1; c.hm[1] = 1; c.hm_L[1] = KA; c.hm_ltot[1] = NKEYS;
    gemm_bf16<false><<<dim3(14, KAPAD / 128), blk, 0, stream>>>(
        hadb, nullptr, WtA + (size_t)3 * DD, c);
  }
  // 4) T-group GEMM, ONE launch, f32 A fused, XCD-swizzled (gridDim.y=256, %8==0)
  {
    EpiCfg c = {};
    c.bias[0] = bkt; c.outB[0] = kall + (size_t)(TT + KA) * HD; c.epi[0] = EPI_ROPE;
    c.pos_mod[0] = KT; c.hm[0] = 1; c.hm_L[0] = KT; c.hm_ltot[0] = NKEYS;
    c.bias[1] = bvt; c.outB[1] = vall + (size_t)(TT + KA) * HD; c.epi[1] = EPI_NONE;
    c.pos_mod[1] = 1; c.hm[1] = 1; c.hm_L[1] = KT; c.hm_ltot[1] = NKEYS;
    c.row_off = 0;
    c.swz = 1;
    gemm_bf16<true><<<dim3(14, BB * KT / 128), blk, 0, stream>>>(
        nullptr, h_t, WtA + (size_t)5 * DD, c);
  }

  // 5) attention — round-1 proven kernel, 1024 threads/block
  attn_kernel<<<BB * NH, dim3(1024), 0, stream>>>(qb, kall, vall, gate, attn_outb);

  // 6) out-proj + residual (fp32 out), LN (bf16 out), FFN + ReLU (fp32 d_out)
  {
    EpiCfg c = {};
    c.bias[0] = bo; c.outF[0] = yb; c.epi[0] = EPI_RESID; c.pos_mod[0] = 1;
    c.resid = x;
    gemm_bf16<false><<<dim3(7, BB * TT / 128), blk, 0, stream>>>(
        attn_outb, nullptr, WtA + (size_t)7 * DD, c);
  }
  ln_kernel<<<BB * TT, blk, 0, stream>>>(yb, ln_g, ln_b, ynb);
  {
    EpiCfg c = {};
    c.bias[0] = bf_; c.outF[0] = (float*)d_out; c.epi[0] = EPI_RELU; c.pos_mod[0] = 1;
    gemm_bf16<false><<<dim3(7, BB * TT / 128), blk, 0, stream>>>(
        ynb, nullptr, WtA + (size_t)8 * DD, c);
  }
}

// Round 7
// 868.538 us; speedup vs baseline: 1.0174x; 1.0174x over previous
//
#include <hip/hip_runtime.h>
#include <hip/hip_bf16.h>
#include <math.h>

#define DIM 896
#define DD  (DIM * DIM)
#define NH 8
#define HD 112
#define BB 64
#define TT 8
#define KA 65
#define KAPAD 4224   // 64*65 = 4160 padded to 33*128
#define KT 512
#define NKEYS (TT + KA + KT)   // 585

// merged QKV launch segments (S first, then A, then T — S/A hide under T)
#define NS_BLK 84     // S: 21 x 4
#define NA_BLK 462    // A: 14 x 33
#define NT_BLK 3584   // T: 14 x 256 (%8==0 -> bijective XCD swizzle)

#define EPI_NONE  0
#define EPI_ROPE  1
#define EPI_RESID 2
#define EPI_RELU  3

// -log2(10000)/56
#define NEG_L2_10K_OVER_56 (-0.2373327285062406f)

#ifndef __has_builtin
#define __has_builtin(x) 0
#endif
#if __has_builtin(__builtin_amdgcn_global_load_lds)
#define HAS_GLL 1
#else
#define HAS_GLL 0
#endif

typedef __attribute__((ext_vector_type(8))) short bf16x8_t;   // 8 bf16 (4 VGPRs)
typedef __attribute__((ext_vector_type(4))) float f32x4_t;    // MFMA accumulator

__device__ __forceinline__ short f2bf(float f) {
  unsigned u = __float_as_uint(f);
  u += 0x7fffu + ((u >> 16) & 1u);
  return (short)(u >> 16);
}
__device__ __forceinline__ float bf2f(short s) {
  return __uint_as_float(((unsigned)(unsigned short)s) << 16);
}
// 2x f32 -> packed bf16 pair (RNE; bit-identical to f2bf for normals).
__device__ __forceinline__ unsigned cvt_pk_bf16(float lo, float hi) {
  unsigned r;
  asm("v_cvt_pk_bf16_f32 %0, %1, %2" : "=v"(r) : "v"(lo), "v"(hi));
  return r;
}
// 16-B global -> LDS direct copy. dest = lbase + lane*16B (wave-uniform base).
__device__ __forceinline__ void gll16(const short* g, short* lbase, int lane) {
#if HAS_GLL
  __builtin_amdgcn_global_load_lds(
      (const __attribute__((address_space(1))) unsigned*)g,
      (__attribute__((address_space(3))) unsigned*)lbase, 16, 0, 0);
#else
  *(bf16x8_t*)(lbase + lane * 8) = *(const bf16x8_t*)g;
#endif
}

// ---------------- 9-way weight transpose: W[k][n] f32 -> Wt[n][k] bf16 ----------------
struct W9 { const float* w[9]; };

__global__ __launch_bounds__(256) void wtrans(W9 ws, short* __restrict__ Wt)
{
  __shared__ float t[32][33];
  const float* W = ws.w[blockIdx.z];
  short* dst = Wt + (size_t)blockIdx.z * DD;
  const int bx = blockIdx.x, by = blockIdx.y;
  const int tx = threadIdx.x & 31, ty = threadIdx.x >> 5;
#pragma unroll
  for (int i = 0; i < 4; ++i)
    t[ty + i * 8][tx] = W[(size_t)(by * 32 + ty + i * 8) * DIM + bx * 32 + tx];
  __syncthreads();
#pragma unroll
  for (int i = 0; i < 4; ++i)
    dst[(size_t)(bx * 32 + ty + i * 8) * DIM + by * 32 + tx] = f2bf(t[tx][ty + i * 8]);
}

// ---------------- h_ad = concat(h_a, p) -> bf16, zero-padded to 4224 rows ----------------
__global__ __launch_bounds__(256) void build_had(
    const float* __restrict__ h_a, const float* __restrict__ p,
    short* __restrict__ had)
{
  const int i = blockIdx.x * 256 + threadIdx.x;  // one per 8 elements
  const int total = KAPAD * DIM / 8;
  if (i >= total) return;
  const int c = (i % 112) * 8;
  const int row = i / 112;
  bf16x8_t o;
  if (row >= BB * KA) {
#pragma unroll
    for (int j = 0; j < 8; ++j) o[j] = 0;
  } else {
    const int b = row / KA, j = row % KA;
    const float* src = (j < KA - 1) ? h_a + ((size_t)b * (KA - 1) + j) * DIM + c
                                    : p + (size_t)b * DIM + c;
    const float4 a = *(const float4*)src;
    const float4 d = *(const float4*)(src + 4);
    o[0] = f2bf(a.x); o[1] = f2bf(a.y); o[2] = f2bf(a.z); o[3] = f2bf(a.w);
    o[4] = f2bf(d.x); o[5] = f2bf(d.y); o[6] = f2bf(d.z); o[7] = f2bf(d.w);
  }
  ((bf16x8_t*)had)[i] = o;
}

// ---------------- MFMA GEMM core (r5-proven 1-phase m97 structure) ----------------
// C[128 x 128] tile of A[M x 896] @ Wt[N x 896](n-major) + bias; 4 waves x (4x4 of
// 16x16x32). af32: A staged from f32 with cvt_pk + issue-early reg prefetch.
// doLN: f32 staging additionally applies (v - mu)*rs*g[k] + beta[k] (fused LayerNorm).
struct EpiCfg {
  const float* bias[3];
  float* outF[3];
  short* outB[3];
  const float* resid;
  int epi[3];
  int pos_mod[3];
  int row_off;
  int hm[3];       // head-major store flag
  int hm_L[3];     // rows per batch (grow decode)
  int hm_ltot[3];  // row stride per (b,h) in the destination
};

__device__ __forceinline__ void gemm_body(
    short* As, short* Bs,
    const short* A, const float* Af, const short* Wt,
    const EpiCfg& cfg, int bx, int by, bool af32,
    bool doLN, float mu0, float rs0, float mu1, float rs1,
    const float* lngam, const float* lnbet)
{
  const int tid = threadIdx.x;
  const int wave = tid >> 6, lane = tid & 63;
  const int sub = bx / 7;
  const int col0 = (bx % 7) * 128;
  const int row0 = by * 128;
  const int wm = wave >> 1, wn = wave & 1;
  const int lm = lane & 15, lq = lane >> 4;

  // staging source: lane -> row-in-16 = lane>>2, k-octet = (lane&3)*8
  const int sm = lane >> 2, sk = (lane & 3) * 8;
  const short* Wg0 = Wt + (size_t)(sub * DIM + col0 + wave * 32 + sm) * DIM + sk;
  const short* Wg1 = Wg0 + (size_t)16 * DIM;

  const short* Ag0 = nullptr;
  const short* Ag1 = nullptr;
  const float* af0 = nullptr;
  const float* af1 = nullptr;
  const int am = tid >> 2, ako = (tid & 3) * 8;
  float4 c0a, c0b, c1a, c1b;            // current K-step A data (regs, af32)
  if (af32) {
    af0 = Af + (size_t)(row0 + am) * DIM + ako;
    af1 = af0 + (size_t)64 * DIM;
    c0a = *(const float4*)(af0);
    c0b = *(const float4*)(af0 + 4);
    c1a = *(const float4*)(af1);
    c1b = *(const float4*)(af1 + 4);
  } else {
    Ag0 = A + (size_t)(row0 + wave * 32 + sm) * DIM + sk;
    Ag1 = Ag0 + (size_t)16 * DIM;
  }

  f32x4_t acc[4][4];
#pragma unroll
  for (int i = 0; i < 4; ++i)
#pragma unroll
    for (int j = 0; j < 4; ++j) acc[i][j] = (f32x4_t){0.f, 0.f, 0.f, 0.f};

  for (int k0 = 0; k0 < DIM; k0 += 32) {
    __syncthreads();
    if (af32) {
      // issue next K-step's loads FIRST (in flight across cvt + MFMA phase)
      const int kn = (k0 + 32 < DIM) ? (k0 + 32) : 0;
      const float4 n0a = *(const float4*)(af0 + kn);
      const float4 n0b = *(const float4*)(af0 + kn + 4);
      const float4 n1a = *(const float4*)(af1 + kn);
      const float4 n1b = *(const float4*)(af1 + kn + 4);
      float e0[8] = {c0a.x, c0a.y, c0a.z, c0a.w, c0b.x, c0b.y, c0b.z, c0b.w};
      float e1[8] = {c1a.x, c1a.y, c1a.z, c1a.w, c1b.x, c1b.y, c1b.z, c1b.w};
      if (doLN) {
#pragma unroll
        for (int j = 0; j < 8; ++j) {
          const int k = k0 + ako + j;
          const float g = lngam[k], b = lnbet[k];
          e0[j] = (e0[j] - mu0) * rs0 * g + b;
          e1[j] = (e1[j] - mu1) * rs1 * g + b;
        }
      }
      uint4 w;
      w.x = cvt_pk_bf16(e0[0], e0[1]); w.y = cvt_pk_bf16(e0[2], e0[3]);
      w.z = cvt_pk_bf16(e0[4], e0[5]); w.w = cvt_pk_bf16(e0[6], e0[7]);
      *(uint4*)&As[tid * 8] = w;
      w.x = cvt_pk_bf16(e1[0], e1[1]); w.y = cvt_pk_bf16(e1[2], e1[3]);
      w.z = cvt_pk_bf16(e1[4], e1[5]); w.w = cvt_pk_bf16(e1[6], e1[7]);
      *(uint4*)&As[(tid + 256) * 8] = w;
      c0a = n0a; c0b = n0b; c1a = n1a; c1b = n1b;
    } else {
      gll16(Ag0 + k0, &As[(wave * 32) * 32], lane);
      gll16(Ag1 + k0, &As[(wave * 32 + 16) * 32], lane);
    }
    gll16(Wg0 + k0, &Bs[(wave * 32) * 32], lane);
    gll16(Wg1 + k0, &Bs[(wave * 32 + 16) * 32], lane);
    __syncthreads();

    bf16x8_t afr[4], bfr[4];
#pragma unroll
    for (int t = 0; t < 4; ++t)
      afr[t] = *(const bf16x8_t*)&As[(wm * 64 + t * 16 + lm) * 32 + lq * 8];
#pragma unroll
    for (int t = 0; t < 4; ++t)
      bfr[t] = *(const bf16x8_t*)&Bs[(wn * 64 + t * 16 + lm) * 32 + lq * 8];
#pragma unroll
    for (int tm = 0; tm < 4; ++tm)
#pragma unroll
      for (int tn = 0; tn < 4; ++tn)
        acc[tm][tn] = __builtin_amdgcn_mfma_f32_16x16x32_bf16(
            afr[tm], bfr[tn], acc[tm][tn], 0, 0, 0);
  }

  // epilogue — C/D frag: row = lq*4 + reg, col = lm (per 16x16 tile)
  const float* bias = cfg.bias[sub];
  float* outF = cfg.outF[sub];
  short* outB = cfg.outB[sub];
  const int epi = cfg.epi[sub], pm = cfg.pos_mod[sub];
  const int hm = cfg.hm[sub];
  const int L = cfg.hm_L[sub], ltot = cfg.hm_ltot[sub];
  int gb[4][4], gl[4][4];
  if (hm) {
#pragma unroll
    for (int tm = 0; tm < 4; ++tm) {
      const int g = cfg.row_off + row0 + wm * 64 + tm * 16 + lq * 4;
      int bq2 = g / L;
      int l = g - bq2 * L;
#pragma unroll
      for (int r = 0; r < 4; ++r) {
        gb[tm][r] = bq2; gl[tm][r] = l;
        if (++l == L) { l = 0; ++bq2; }
      }
    }
  }
#pragma unroll
  for (int tn = 0; tn < 4; ++tn) {
    const int col = col0 + wn * 64 + tn * 16 + lm;
    const float bv = bias[col];
    int hcol = 0, dcol = 0;
    if (hm) { hcol = col / HD; dcol = col - hcol * HD; }
    float fr = 0.f, sgn = 0.f;
    if (epi == EPI_ROPE) {
      const int d0 = col % HD;
      fr = exp2f((float)(d0 % 56) * NEG_L2_10K_OVER_56);
      sgn = (d0 & 1) ? 1.f : -1.f;
    }
#pragma unroll
    for (int tm = 0; tm < 4; ++tm) {
#pragma unroll
      for (int r = 0; r < 4; ++r) {
        const int grow = cfg.row_off + row0 + wm * 64 + tm * 16 + lq * 4 + r;
        float v = acc[tm][tn][r] + bv;
        if (epi == EPI_ROPE) {
          const float prt = __shfl_xor(v, 1);  // partner col (lane^1), pre-rope
          const int pos = hm ? gl[tm][r] : (grow % pm);
          float s, c;
          __sincosf((float)pos * fr, &s, &c);
          v = v * c + sgn * prt * s;
        } else if (epi == EPI_RESID) {
          v += cfg.resid[(size_t)grow * DIM + col];
        } else if (epi == EPI_RELU) {
          v = fmaxf(v, 0.f);
        }
        if (hm) {
          if (gb[tm][r] < BB)
            outB[((size_t)(gb[tm][r] * NH + hcol) * ltot + gl[tm][r]) * HD + dcol] =
                f2bf(v);
        } else if (outB) {
          outB[(size_t)grow * DIM + col] = f2bf(v);
        } else {
          outF[(size_t)grow * DIM + col] = v;
        }
      }
    }
  }
}

// ---------------- merged S+A+T QKV GEMM: one launch, 4130 blocks ----------------
__global__ __launch_bounds__(256) void qkv_gemm(
    const float* __restrict__ x, const short* __restrict__ hadb,
    const float* __restrict__ h_t, const short* __restrict__ Wt,
    EpiCfg cS, EpiCfg cA, EpiCfg cT)
{
  __shared__ __align__(16) short As[128 * 32];
  __shared__ __align__(16) short Bs[128 * 32];
  const int b = blockIdx.x;
  int bx, by;
  const short* A = nullptr;
  const float* Af = nullptr;
  const short* W;
  if (b < NS_BLK) {                    // S: x(f32) @ [Wq|Wks|Wvs]
    bx = b % 21; by = b / 21;
    Af = x; W = Wt;
  } else if (b < NS_BLK + NA_BLK) {    // A: hadb(bf16) @ [Wka|Wva]
    const int t = b - NS_BLK;
    bx = t % 14; by = t / 14;
    A = hadb; W = Wt + (size_t)3 * DD;
  } else {                             // T: h_t(f32) @ [Wkt|Wvt], XCD-swizzled
    const int t = b - NS_BLK - NA_BLK;
    const int xcd = t & 7, ixd = t >> 3;   // 3584 = 8 * 448, rpx = 32
    bx = ixd % 14; by = xcd * 32 + ixd / 14;
    Af = h_t; W = Wt + (size_t)5 * DD;
  }
  const EpiCfg& c = (b < NS_BLK) ? cS : (b < NS_BLK + NA_BLK ? cA : cT);
  gemm_body(As, Bs, A, Af, W, c, bx, by, Af != nullptr,
            false, 0.f, 0.f, 0.f, 0.f, nullptr, nullptr);
}

// ---------------- single-problem GEMM (bf16 A): out-proj ----------------
__global__ __launch_bounds__(256) void gemm_one(
    const short* __restrict__ A, const short* __restrict__ Wt, EpiCfg cfg)
{
  __shared__ __align__(16) short As[128 * 32];
  __shared__ __align__(16) short Bs[128 * 32];
  gemm_body(As, Bs, A, nullptr, Wt, cfg, blockIdx.x, blockIdx.y, false,
            false, 0.f, 0.f, 0.f, 0.f, nullptr, nullptr);
}

// ---------------- FFN GEMM with fused LayerNorm on the A-staging ----------------
// A = LN(y): block pre-pass computes per-row mean/rstd (K range == full LN row),
// staging applies (v-mu)*rs*g[k]+beta[k] before cvt to bf16.
__global__ __launch_bounds__(256) void gemm_ffn(
    const float* __restrict__ Y, const float* __restrict__ lng,
    const float* __restrict__ lnb, const short* __restrict__ Wt, EpiCfg cfg)
{
  __shared__ __align__(16) short As[128 * 32];
  __shared__ __align__(16) short Bs[128 * 32];
  __shared__ float glds[DIM], blds[DIM];
  __shared__ float smu[128], srs[128];
  const int tid = threadIdx.x;
  const int row0 = blockIdx.y * 128;
  for (int i = tid; i < DIM; i += 256) { glds[i] = lng[i]; blds[i] = lnb[i]; }
  {
    const int r = tid >> 1, h = tid & 1;   // 2 threads per row, 448 elems each
    const float* rp = Y + (size_t)(row0 + r) * DIM + h * 448;
    float s = 0.f, q = 0.f;
    for (int i = 0; i < 448; i += 4) {
      const float4 v = *(const float4*)(rp + i);
      s += v.x + v.y + v.z + v.w;
      q = fmaf(v.x, v.x, fmaf(v.y, v.y, fmaf(v.z, v.z, fmaf(v.w, v.w, q))));
    }
    s += __shfl_xor(s, 1);
    q += __shfl_xor(q, 1);
    if (h == 0) {
      const float mu = s * (1.f / DIM);
      const float var = q * (1.f / DIM) - mu * mu;
      smu[r] = mu;
      srs[r] = 1.f / sqrtf(var + 1e-5f);
    }
  }
  __syncthreads();
  const int am = tid >> 2;
  gemm_body(As, Bs, nullptr, Y, Wt, cfg, blockIdx.x, blockIdx.y, true,
            true, smu[am], srs[am], smu[am + 64], srs[am + 64], glds, blds);
}

// ---------------- attention: one 1024-thread block per (b,h) (round-1 proven) -------
#define SCP 10   // score row stride (floats): conflict-free (gcd(10,32)=2), float2-aligned

__global__ __launch_bounds__(1024, 8) void attn_kernel(
    const short* __restrict__ q, const short* __restrict__ kall,
    const short* __restrict__ vall, const float* __restrict__ gate,
    short* __restrict__ out)
{
  __shared__ __align__(16) float qs[TT * HD];        // 3584 B
  __shared__ __align__(16) float sc[NKEYS * SCP];    // 23400 B, [k][t] padded
  __shared__ float red[TT * TT * HD];                // 28672 B, [g][t][d]
  __shared__ float isum[TT];
  const int tid = threadIdx.x;
  const int bh = blockIdx.x;
  const float scale = 0.09449111825230681f;  // 1/sqrt(112)
  const float rg = tanhf(gate[0]);

  // phase 0: q -> fp32 LDS (contiguous head-major load)
  if (tid < TT * HD) qs[tid] = bf2f(q[(size_t)bh * (TT * HD) + tid]);
  __syncthreads();

  // phase 1: scores — one thread per key, contiguous 224 B key row
  if (tid < NKEYS) {
    const int k = tid;
    const short* kp = kall + ((size_t)bh * NKEYS + k) * HD;
    float dot[TT] = {};
    for (int d8 = 0; d8 < HD; d8 += 8) {
      const bf16x8_t kv8 = *(const bf16x8_t*)(kp + d8);
      float kf[8];
#pragma unroll
      for (int j = 0; j < 8; ++j) kf[j] = bf2f(kv8[j]);
#pragma unroll
      for (int t = 0; t < TT; ++t) {
        const float4 qa = *(const float4*)&qs[t * HD + d8];
        const float4 qb4 = *(const float4*)&qs[t * HD + d8 + 4];
        dot[t] = fmaf(qa.x, kf[0], dot[t]);
        dot[t] = fmaf(qa.y, kf[1], dot[t]);
        dot[t] = fmaf(qa.z, kf[2], dot[t]);
        dot[t] = fmaf(qa.w, kf[3], dot[t]);
        dot[t] = fmaf(qb4.x, kf[4], dot[t]);
        dot[t] = fmaf(qb4.y, kf[5], dot[t]);
        dot[t] = fmaf(qb4.z, kf[6], dot[t]);
        dot[t] = fmaf(qb4.w, kf[7], dot[t]);
      }
    }
    const float s = (k >= TT + KA) ? scale * rg : scale;
#pragma unroll
    for (int t = 0; t < TT; ++t) sc[k * SCP + t] = dot[t] * s;
  }
  __syncthreads();

  // phase 2: softmax per t-row, one wave per row
  const int wave = tid >> 6, lane = tid & 63;
  if (wave < TT) {
    const int t = wave;
    float m = -1e30f;
    for (int k = lane; k < NKEYS; k += 64) m = fmaxf(m, sc[k * SCP + t]);
#pragma unroll
    for (int o = 32; o >= 1; o >>= 1) m = fmaxf(m, __shfl_xor(m, o));
    float sum = 0.f;
    for (int k = lane; k < NKEYS; k += 64) {
      const float e = expf(sc[k * SCP + t] - m);
      sc[k * SCP + t] = e;
      sum += e;
    }
#pragma unroll
    for (int o = 32; o >= 1; o >>= 1) sum += __shfl_xor(sum, o);
    if (lane == 0) isum[t] = 1.f / sum;
  }
  __syncthreads();

  // phase 3: PV partials — keys split 8 ways, each thread owns (group g, dim d)
  if (tid < TT * HD) {
    const int g = tid / HD, d = tid - (tid / HD) * HD;
    const int kb = (g * NKEYS) / TT, ke = ((g + 1) * NKEYS) / TT;
    const short* vp = vall + (size_t)bh * (NKEYS * HD) + d;
    float acc[TT] = {};
    for (int k = kb; k < ke; ++k) {
      const float vv = bf2f(vp[(size_t)k * HD]);
      const float2 s0 = *(const float2*)&sc[k * SCP];
      const float2 s1 = *(const float2*)&sc[k * SCP + 2];
      const float2 s2 = *(const float2*)&sc[k * SCP + 4];
      const float2 s3 = *(const float2*)&sc[k * SCP + 6];
      acc[0] = fmaf(s0.x, vv, acc[0]);
      acc[1] = fmaf(s0.y, vv, acc[1]);
      acc[2] = fmaf(s1.x, vv, acc[2]);
      acc[3] = fmaf(s1.y, vv, acc[3]);
      acc[4] = fmaf(s2.x, vv, acc[4]);
      acc[5] = fmaf(s2.y, vv, acc[5]);
      acc[6] = fmaf(s3.x, vv, acc[6]);
      acc[7] = fmaf(s3.y, vv, acc[7]);
    }
#pragma unroll
    for (int t = 0; t < TT; ++t) red[(g * TT + t) * HD + d] = acc[t];
  }
  __syncthreads();

  // phase 4: cross-group reduce + normalize + store (row-major for out-proj)
  if (tid < TT * HD) {
    const int t = tid / HD, d = tid - (tid / HD) * HD;
    float a = 0.f;
#pragma unroll
    for (int g = 0; g < TT; ++g) a += red[(g * TT + t) * HD + d];
    out[((size_t)(bh >> 3) * TT + t) * DIM + (bh & 7) * HD + d] = f2bf(a * isum[t]);
  }
}

// ---------------- launch ----------------
extern "C" void kernel_launch(void* const* d_in, const int* in_sizes, int n_in,
                              void* d_out, int out_size, void* d_ws, size_t ws_size,
                              hipStream_t stream)
{
  const float* x   = (const float*)d_in[0];
  const float* h_a = (const float*)d_in[1];
  const float* h_t = (const float*)d_in[2];
  const float* p   = (const float*)d_in[3];
  const float* Wq  = (const float*)d_in[4];  const float* bq  = (const float*)d_in[5];
  const float* Wks = (const float*)d_in[6];  const float* bks = (const float*)d_in[7];
  const float* Wvs = (const float*)d_in[8];  const float* bvs = (const float*)d_in[9];
  const float* Wka = (const float*)d_in[10]; const float* bka = (const float*)d_in[11];
  const float* Wva = (const float*)d_in[12]; const float* bva = (const float*)d_in[13];
  const float* Wkt = (const float*)d_in[14]; const float* bkt = (const float*)d_in[15];
  const float* Wvt = (const float*)d_in[16]; const float* bvt = (const float*)d_in[17];
  const float* Wo  = (const float*)d_in[18]; const float* bo  = (const float*)d_in[19];
  const float* Wf  = (const float*)d_in[20]; const float* bf_ = (const float*)d_in[21];
  const float* gate = (const float*)d_in[22];
  const float* ln_g = (const float*)d_in[23];
  const float* ln_b = (const float*)d_in[24];

  // ---- workspace layout (bytes) ----
  const size_t SZ_HAD = (size_t)KAPAD * DIM * 2;            // bf16
  const size_t SZ_SM  = (size_t)BB * TT * DIM * 2;          // bf16 small [512 x 896]
  const size_t SZ_KV  = (size_t)BB * NH * NKEYS * HD * 2;   // bf16 [b][h][585][112]
  const size_t SZ_WT  = (size_t)9 * DD * 2;                 // 9 weights bf16
  const size_t needed = SZ_HAD + SZ_SM * 2 + SZ_KV * 2 + SZ_WT
                        + (size_t)BB * TT * DIM * 4;        // + yb fp32
  if (ws_size < needed) return;  // fail loud, not UB

  char* wsp = (char*)d_ws;
  short* hadb = (short*)wsp; wsp += SZ_HAD;
  short* qb   = (short*)wsp; wsp += SZ_SM;   // head-major [b][h][8][112]
  short* kall = (short*)wsp; wsp += SZ_KV;   // head-major [b][h][585][112]
  short* vall = (short*)wsp; wsp += SZ_KV;
  short* WtA  = (short*)wsp; wsp += SZ_WT;
  short* attn_outb = (short*)wsp; wsp += SZ_SM;
  float* yb   = (float*)wsp; wsp += (size_t)BB * TT * DIM * 4;

  dim3 blk(256);

  // 0) transpose all 9 weights -> bf16 [n][k], concatenated
  W9 w9; const float* Ws[9] = {Wq, Wks, Wvs, Wka, Wva, Wkt, Wvt, Wo, Wf};
  for (int i = 0; i < 9; ++i) w9.w[i] = Ws[i];
  wtrans<<<dim3(28, 28, 9), blk, 0, stream>>>(w9, WtA);

  // 1) h_ad -> bf16
  build_had<<<(KAPAD * DIM / 8 + 255) / 256, blk, 0, stream>>>(h_a, p, hadb);

  // 2) merged QKV GEMM: S + A + T in one launch
  EpiCfg cS = {};
  cS.bias[0] = bq;  cS.outB[0] = qb;   cS.epi[0] = EPI_ROPE; cS.pos_mod[0] = TT;
  cS.hm[0] = 1; cS.hm_L[0] = TT; cS.hm_ltot[0] = TT;
  cS.bias[1] = bks; cS.outB[1] = kall; cS.epi[1] = EPI_ROPE; cS.pos_mod[1] = TT;
  cS.hm[1] = 1; cS.hm_L[1] = TT; cS.hm_ltot[1] = NKEYS;
  cS.bias[2] = bvs; cS.outB[2] = vall; cS.epi[2] = EPI_NONE; cS.pos_mod[2] = 1;
  cS.hm[2] = 1; cS.hm_L[2] = TT; cS.hm_ltot[2] = NKEYS;

  EpiCfg cA = {};
  cA.bias[0] = bka; cA.outB[0] = kall + (size_t)TT * HD; cA.epi[0] = EPI_ROPE;
  cA.pos_mod[0] = KA; cA.hm[0] = 1; cA.hm_L[0] = KA; cA.hm_ltot[0] = NKEYS;
  cA.bias[1] = bva; cA.outB[1] = vall + (size_t)TT * HD; cA.epi[1] = EPI_NONE;
  cA.pos_mod[1] = 1; cA.hm[1] = 1; cA.hm_L[1] = KA; cA.hm_ltot[1] = NKEYS;

  EpiCfg cT = {};
  cT.bias[0] = bkt; cT.outB[0] = kall + (size_t)(TT + KA) * HD; cT.epi[0] = EPI_ROPE;
  cT.pos_mod[0] = KT; cT.hm[0] = 1; cT.hm_L[0] = KT; cT.hm_ltot[0] = NKEYS;
  cT.bias[1] = bvt; cT.outB[1] = vall + (size_t)(TT + KA) * HD; cT.epi[1] = EPI_NONE;
  cT.pos_mod[1] = 1; cT.hm[1] = 1; cT.hm_L[1] = KT; cT.hm_ltot[1] = NKEYS;

  qkv_gemm<<<dim3(NS_BLK + NA_BLK + NT_BLK), blk, 0, stream>>>(
      x, hadb, h_t, WtA, cS, cA, cT);

  // 3) attention — proven kernel, 1024 threads/block
  attn_kernel<<<BB * NH, dim3(1024), 0, stream>>>(qb, kall, vall, gate, attn_outb);

  // 4) out-proj + residual (fp32 out)
  {
    EpiCfg c = {};
    c.bias[0] = bo; c.outF[0] = yb; c.epi[0] = EPI_RESID; c.pos_mod[0] = 1;
    c.resid = x;
    gemm_one<<<dim3(7, BB * TT / 128), blk, 0, stream>>>(
        attn_outb, WtA + (size_t)7 * DD, c);
  }
  // 5) FFN with fused LayerNorm + ReLU (fp32 d_out)
  {
    EpiCfg c = {};
    c.bias[0] = bf_; c.outF[0] = (float*)d_out; c.epi[0] = EPI_RELU; c.pos_mod[0] = 1;
    gemm_ffn<<<dim3(7, BB * TT / 128), blk, 0, stream>>>(
        yb, ln_g, ln_b, WtA + (size_t)8 * DD, c);
  }
}

// Round 8
// 756.084 us; speedup vs baseline: 1.1687x; 1.1487x over previous
//
#include <hip/hip_runtime.h>
#include <hip/hip_bf16.h>
#include <math.h>

#define DIM 896
#define DD  (DIM * DIM)
#define NH 8
#define HD 112
#define BB 64
#define TT 8
#define KA 65
#define KAPAD 4224   // 64*65 = 4160 padded to 33*128
#define KT 512
#define NKEYS (TT + KA + KT)   // 585

#define EPI_NONE  0
#define EPI_ROPE  1
#define EPI_RESID 2
#define EPI_RELU  3

// -log2(10000)/56
#define NEG_L2_10K_OVER_56 (-0.2373327285062406f)

#ifndef __has_builtin
#define __has_builtin(x) 0
#endif
#if __has_builtin(__builtin_amdgcn_global_load_lds)
#define HAS_GLL 1
#else
#define HAS_GLL 0
#endif

typedef __attribute__((ext_vector_type(8))) short bf16x8_t;   // 8 bf16 (4 VGPRs)
typedef __attribute__((ext_vector_type(4))) float f32x4_t;    // MFMA accumulator

__device__ __forceinline__ short f2bf(float f) {
  unsigned u = __float_as_uint(f);
  u += 0x7fffu + ((u >> 16) & 1u);
  return (short)(u >> 16);
}
__device__ __forceinline__ float bf2f(short s) {
  return __uint_as_float(((unsigned)(unsigned short)s) << 16);
}
// 2x f32 -> packed bf16 pair (RNE; bit-identical to f2bf for normals).
__device__ __forceinline__ unsigned cvt_pk_bf16(float lo, float hi) {
  unsigned r;
  asm("v_cvt_pk_bf16_f32 %0, %1, %2" : "=v"(r) : "v"(lo), "v"(hi));
  return r;
}
// 16-B global -> LDS direct copy. dest = lbase + lane*16B (wave-uniform base).
__device__ __forceinline__ void gll16(const short* g, short* lbase, int lane) {
#if HAS_GLL
  __builtin_amdgcn_global_load_lds(
      (const __attribute__((address_space(1))) unsigned*)g,
      (__attribute__((address_space(3))) unsigned*)lbase, 16, 0, 0);
#else
  *(bf16x8_t*)(lbase + lane * 8) = *(const bf16x8_t*)g;
#endif
}

// ---------------- 9-way weight transpose: W[k][n] f32 -> Wt[n][k] bf16 ----------------
struct W9 { const float* w[9]; };

__global__ __launch_bounds__(256) void wtrans(W9 ws, short* __restrict__ Wt)
{
  __shared__ float t[32][33];
  const float* W = ws.w[blockIdx.z];
  short* dst = Wt + (size_t)blockIdx.z * DD;
  const int bx = blockIdx.x, by = blockIdx.y;
  const int tx = threadIdx.x & 31, ty = threadIdx.x >> 5;
#pragma unroll
  for (int i = 0; i < 4; ++i)
    t[ty + i * 8][tx] = W[(size_t)(by * 32 + ty + i * 8) * DIM + bx * 32 + tx];
  __syncthreads();
#pragma unroll
  for (int i = 0; i < 4; ++i)
    dst[(size_t)(bx * 32 + ty + i * 8) * DIM + by * 32 + tx] = f2bf(t[tx][ty + i * 8]);
}

// ---------------- h_ad = concat(h_a, p) -> bf16, zero-padded to 4224 rows ----------------
__global__ __launch_bounds__(256) void build_had(
    const float* __restrict__ h_a, const float* __restrict__ p,
    short* __restrict__ had)
{
  const int i = blockIdx.x * 256 + threadIdx.x;  // one per 8 elements
  const int total = KAPAD * DIM / 8;
  if (i >= total) return;
  const int c = (i % 112) * 8;
  const int row = i / 112;
  bf16x8_t o;
  if (row >= BB * KA) {
#pragma unroll
    for (int j = 0; j < 8; ++j) o[j] = 0;
  } else {
    const int b = row / KA, j = row % KA;
    const float* src = (j < KA - 1) ? h_a + ((size_t)b * (KA - 1) + j) * DIM + c
                                    : p + (size_t)b * DIM + c;
    const float4 a = *(const float4*)src;
    const float4 d = *(const float4*)(src + 4);
    o[0] = f2bf(a.x); o[1] = f2bf(a.y); o[2] = f2bf(a.z); o[3] = f2bf(a.w);
    o[4] = f2bf(d.x); o[5] = f2bf(d.y); o[6] = f2bf(d.z); o[7] = f2bf(d.w);
  }
  ((bf16x8_t*)had)[i] = o;
}

// ---------------- MFMA GEMM core: BK=64 single-buffer + XOR-swizzled LDS ----------
// C[128 x 128] tile of A[M x 896] @ Wt[N x 896](n-major) + bias.
// LDS layout [row][64] shorts (128 B rows) with granule swizzle: the 16-B granule
// at physical slot p of row r holds logical granule p ^ (r & 7). Staging writes
// linear LDS (gll16) with pre-swizzled GLOBAL source granule; frag reads apply the
// same XOR -> 2-way (free) bank aliasing instead of 16-way conflicts.
// 14 K-steps (vs 28 at BK=32): half the barrier-drain stalls, 32 MFMAs per step.
struct EpiCfg {
  const float* bias[3];
  float* outF[3];
  short* outB[3];
  const float* resid;
  int epi[3];
  int pos_mod[3];
  int row_off;
  int hm[3];       // head-major store flag
  int hm_L[3];     // rows per batch (grow decode)
  int hm_ltot[3];  // row stride per (b,h) in the destination
  int swz;         // XCD swizzle on/off (T-GEMM)
};

template <bool AF32, bool DOLN>
__device__ __forceinline__ void gemm_body(
    short* As, short* Bs,
    const short* A, const float* Af, const short* Wt,
    const EpiCfg& cfg, int bx, int by,
    const float* smu, const float* srs,
    const float* lngam, const float* lnbet)
{
  const int tid = threadIdx.x;
  const int wave = tid >> 6, lane = tid & 63;
  const int sub = bx / 7;
  const int col0 = (bx % 7) * 128;
  const int row0 = by * 128;
  const int wm = wave >> 1, wn = wave & 1;
  const int lm = lane & 15, lq = lane >> 4;

  // gll16 staging: one call = 8 rows x 128 B. lane -> row-in-8 = lane>>3,
  // physical granule = lane&7, so load logical granule (lane&7)^(row&7).
  const int sr = lane >> 3;
  const int sg = (lane & 7) ^ sr;          // pre-swizzled source granule
  const short* Wg = Wt + (size_t)(sub * DIM + col0 + wave * 32 + sr) * DIM + sg * 8;
  const short* Ag = nullptr;
  if constexpr (!AF32)
    Ag = A + (size_t)(row0 + wave * 32 + sr) * DIM + sg * 8;

  f32x4_t acc[4][4];
#pragma unroll
  for (int i = 0; i < 4; ++i)
#pragma unroll
    for (int j = 0; j < 4; ++j) acc[i][j] = (f32x4_t){0.f, 0.f, 0.f, 0.f};

  for (int k0 = 0; k0 < DIM; k0 += 64) {
    __syncthreads();
    if constexpr (AF32) {
      // 4 chunks/thread: chunk c = tid + 256*j -> row = c>>3, logical granule g = c&7
#pragma unroll
      for (int j = 0; j < 4; ++j) {
        const int c = tid + 256 * j;
        const int row = c >> 3, g = c & 7;
        const float* srcp = Af + (size_t)(row0 + row) * DIM + k0 + g * 8;
        const float4 a0 = *(const float4*)srcp;
        const float4 a1 = *(const float4*)(srcp + 4);
        float e[8] = {a0.x, a0.y, a0.z, a0.w, a1.x, a1.y, a1.z, a1.w};
        if constexpr (DOLN) {
          const float mu = smu[row], rs = srs[row];
#pragma unroll
          for (int q = 0; q < 8; ++q) {
            const int k = k0 + g * 8 + q;
            e[q] = (e[q] - mu) * rs * lngam[k] + lnbet[k];
          }
        }
        uint4 w;
        w.x = cvt_pk_bf16(e[0], e[1]); w.y = cvt_pk_bf16(e[2], e[3]);
        w.z = cvt_pk_bf16(e[4], e[5]); w.w = cvt_pk_bf16(e[6], e[7]);
        *(uint4*)&As[row * 64 + ((g ^ (row & 7)) << 3)] = w;
      }
    } else {
#pragma unroll
      for (int j = 0; j < 4; ++j)
        gll16(Ag + (size_t)(j * 8) * DIM + k0, &As[(wave * 32 + j * 8) * 64], lane);
    }
#pragma unroll
    for (int j = 0; j < 4; ++j)
      gll16(Wg + (size_t)(j * 8) * DIM + k0, &Bs[(wave * 32 + j * 8) * 64], lane);
    __syncthreads();

    bf16x8_t afr[4][2], bfr[4][2];
#pragma unroll
    for (int t = 0; t < 4; ++t) {
      const int ra = wm * 64 + t * 16 + lm;
      const int rb = wn * 64 + t * 16 + lm;
      afr[t][0] = *(const bf16x8_t*)&As[ra * 64 + (((lq) ^ (ra & 7)) << 3)];
      afr[t][1] = *(const bf16x8_t*)&As[ra * 64 + (((4 + lq) ^ (ra & 7)) << 3)];
      bfr[t][0] = *(const bf16x8_t*)&Bs[rb * 64 + (((lq) ^ (rb & 7)) << 3)];
      bfr[t][1] = *(const bf16x8_t*)&Bs[rb * 64 + (((4 + lq) ^ (rb & 7)) << 3)];
    }
#pragma unroll
    for (int kk = 0; kk < 2; ++kk)
#pragma unroll
      for (int tm = 0; tm < 4; ++tm)
#pragma unroll
        for (int tn = 0; tn < 4; ++tn)
          acc[tm][tn] = __builtin_amdgcn_mfma_f32_16x16x32_bf16(
              afr[tm][kk], bfr[tn][kk], acc[tm][tn], 0, 0, 0);
  }

  // epilogue — C/D frag: row = lq*4 + reg, col = lm (per 16x16 tile)
  const float* bias = cfg.bias[sub];
  float* outF = cfg.outF[sub];
  short* outB = cfg.outB[sub];
  const int epi = cfg.epi[sub], pm = cfg.pos_mod[sub];
  const int hm = cfg.hm[sub];
  const int L = cfg.hm_L[sub], ltot = cfg.hm_ltot[sub];
  int gb[4][4], gl[4][4];
  if (hm) {
#pragma unroll
    for (int tm = 0; tm < 4; ++tm) {
      const int g = cfg.row_off + row0 + wm * 64 + tm * 16 + lq * 4;
      int bq2 = g / L;
      int l = g - bq2 * L;
#pragma unroll
      for (int r = 0; r < 4; ++r) {
        gb[tm][r] = bq2; gl[tm][r] = l;
        if (++l == L) { l = 0; ++bq2; }
      }
    }
  }
#pragma unroll
  for (int tn = 0; tn < 4; ++tn) {
    const int col = col0 + wn * 64 + tn * 16 + lm;
    const float bv = bias[col];
    int hcol = 0, dcol = 0;
    if (hm) { hcol = col / HD; dcol = col - hcol * HD; }
    float fr = 0.f, sgn = 0.f;
    if (epi == EPI_ROPE) {
      const int d0 = col % HD;
      fr = exp2f((float)(d0 % 56) * NEG_L2_10K_OVER_56);
      sgn = (d0 & 1) ? 1.f : -1.f;
    }
#pragma unroll
    for (int tm = 0; tm < 4; ++tm) {
#pragma unroll
      for (int r = 0; r < 4; ++r) {
        const int grow = cfg.row_off + row0 + wm * 64 + tm * 16 + lq * 4 + r;
        float v = acc[tm][tn][r] + bv;
        if (epi == EPI_ROPE) {
          const float prt = __shfl_xor(v, 1);  // partner col (lane^1), pre-rope
          const int pos = hm ? gl[tm][r] : (grow % pm);
          float s, c;
          __sincosf((float)pos * fr, &s, &c);
          v = v * c + sgn * prt * s;
        } else if (epi == EPI_RESID) {
          v += cfg.resid[(size_t)grow * DIM + col];
        } else if (epi == EPI_RELU) {
          v = fmaxf(v, 0.f);
        }
        if (hm) {
          if (gb[tm][r] < BB)
            outB[((size_t)(gb[tm][r] * NH + hcol) * ltot + gl[tm][r]) * HD + dcol] =
                f2bf(v);
        } else if (outB) {
          outB[(size_t)grow * DIM + col] = f2bf(v);
        } else {
          outF[(size_t)grow * DIM + col] = v;
        }
      }
    }
  }
}

// ---------------- GEMM kernels (separate launches — r5 proven structure) ----------
template <bool AF32>
__global__ __launch_bounds__(256) void gemm_bf16(
    const short* __restrict__ A, const float* __restrict__ Af,
    const short* __restrict__ Wt, EpiCfg cfg)
{
  __shared__ __align__(16) short As[128 * 64];
  __shared__ __align__(16) short Bs[128 * 64];
  int bx = blockIdx.x, by = blockIdx.y;
  if (cfg.swz) {
    const int nx = gridDim.x;
    const int bid = blockIdx.x + blockIdx.y * nx;   // HW dispatch order
    const int xcd = bid & 7, ixd = bid >> 3;
    const int rpx = gridDim.y >> 3;                 // row panels per XCD
    bx = ixd % nx;
    by = xcd * rpx + ixd / nx;
  }
  gemm_body<AF32, false>(As, Bs, A, Af, Wt, cfg, bx, by,
                         nullptr, nullptr, nullptr, nullptr);
}

// FFN GEMM with fused LayerNorm on the A-staging (A = LN(y); K range == LN row).
__global__ __launch_bounds__(256) void gemm_ffn(
    const float* __restrict__ Y, const float* __restrict__ lng,
    const float* __restrict__ lnb, const short* __restrict__ Wt, EpiCfg cfg)
{
  __shared__ __align__(16) short As[128 * 64];
  __shared__ __align__(16) short Bs[128 * 64];
  __shared__ float glds[DIM], blds[DIM];
  __shared__ float smu[128], srs[128];
  const int tid = threadIdx.x;
  const int row0 = blockIdx.y * 128;
  for (int i = tid; i < DIM; i += 256) { glds[i] = lng[i]; blds[i] = lnb[i]; }
  {
    const int r = tid >> 1, h = tid & 1;   // 2 threads per row, 448 elems each
    const float* rp = Y + (size_t)(row0 + r) * DIM + h * 448;
    float s = 0.f, q = 0.f;
    for (int i = 0; i < 448; i += 4) {
      const float4 v = *(const float4*)(rp + i);
      s += v.x + v.y + v.z + v.w;
      q = fmaf(v.x, v.x, fmaf(v.y, v.y, fmaf(v.z, v.z, fmaf(v.w, v.w, q))));
    }
    s += __shfl_xor(s, 1);
    q += __shfl_xor(q, 1);
    if (h == 0) {
      const float mu = s * (1.f / DIM);
      const float var = q * (1.f / DIM) - mu * mu;
      smu[r] = mu;
      srs[r] = 1.f / sqrtf(var + 1e-5f);
    }
  }
  __syncthreads();
  gemm_body<true, true>(As, Bs, nullptr, Y, Wt, cfg, blockIdx.x, blockIdx.y,
                        smu, srs, glds, blds);
}

// ---------------- attention: one 1024-thread block per (b,h) (round-1 proven) -------
#define SCP 10   // score row stride (floats): conflict-free (gcd(10,32)=2), float2-aligned

__global__ __launch_bounds__(1024, 8) void attn_kernel(
    const short* __restrict__ q, const short* __restrict__ kall,
    const short* __restrict__ vall, const float* __restrict__ gate,
    short* __restrict__ out)
{
  __shared__ __align__(16) float qs[TT * HD];        // 3584 B
  __shared__ __align__(16) float sc[NKEYS * SCP];    // 23400 B, [k][t] padded
  __shared__ float red[TT * TT * HD];                // 28672 B, [g][t][d]
  __shared__ float isum[TT];
  const int tid = threadIdx.x;
  const int bh = blockIdx.x;
  const float scale = 0.09449111825230681f;  // 1/sqrt(112)
  const float rg = tanhf(gate[0]);

  // phase 0: q -> fp32 LDS (contiguous head-major load)
  if (tid < TT * HD) qs[tid] = bf2f(q[(size_t)bh * (TT * HD) + tid]);
  __syncthreads();

  // phase 1: scores — one thread per key, contiguous 224 B key row
  if (tid < NKEYS) {
    const int k = tid;
    const short* kp = kall + ((size_t)bh * NKEYS + k) * HD;
    float dot[TT] = {};
    for (int d8 = 0; d8 < HD; d8 += 8) {
      const bf16x8_t kv8 = *(const bf16x8_t*)(kp + d8);
      float kf[8];
#pragma unroll
      for (int j = 0; j < 8; ++j) kf[j] = bf2f(kv8[j]);
#pragma unroll
      for (int t = 0; t < TT; ++t) {
        const float4 qa = *(const float4*)&qs[t * HD + d8];
        const float4 qb4 = *(const float4*)&qs[t * HD + d8 + 4];
        dot[t] = fmaf(qa.x, kf[0], dot[t]);
        dot[t] = fmaf(qa.y, kf[1], dot[t]);
        dot[t] = fmaf(qa.z, kf[2], dot[t]);
        dot[t] = fmaf(qa.w, kf[3], dot[t]);
        dot[t] = fmaf(qb4.x, kf[4], dot[t]);
        dot[t] = fmaf(qb4.y, kf[5], dot[t]);
        dot[t] = fmaf(qb4.z, kf[6], dot[t]);
        dot[t] = fmaf(qb4.w, kf[7], dot[t]);
      }
    }
    const float s = (k >= TT + KA) ? scale * rg : scale;
#pragma unroll
    for (int t = 0; t < TT; ++t) sc[k * SCP + t] = dot[t] * s;
  }
  __syncthreads();

  // phase 2: softmax per t-row, one wave per row
  const int wave = tid >> 6, lane = tid & 63;
  if (wave < TT) {
    const int t = wave;
    float m = -1e30f;
    for (int k = lane; k < NKEYS; k += 64) m = fmaxf(m, sc[k * SCP + t]);
#pragma unroll
    for (int o = 32; o >= 1; o >>= 1) m = fmaxf(m, __shfl_xor(m, o));
    float sum = 0.f;
    for (int k = lane; k < NKEYS; k += 64) {
      const float e = expf(sc[k * SCP + t] - m);
      sc[k * SCP + t] = e;
      sum += e;
    }
#pragma unroll
    for (int o = 32; o >= 1; o >>= 1) sum += __shfl_xor(sum, o);
    if (lane == 0) isum[t] = 1.f / sum;
  }
  __syncthreads();

  // phase 3: PV partials — keys split 8 ways, each thread owns (group g, dim d)
  if (tid < TT * HD) {
    const int g = tid / HD, d = tid - (tid / HD) * HD;
    const int kb = (g * NKEYS) / TT, ke = ((g + 1) * NKEYS) / TT;
    const short* vp = vall + (size_t)bh * (NKEYS * HD) + d;
    float acc[TT] = {};
    for (int k = kb; k < ke; ++k) {
      const float vv = bf2f(vp[(size_t)k * HD]);
      const float2 s0 = *(const float2*)&sc[k * SCP];
      const float2 s1 = *(const float2*)&sc[k * SCP + 2];
      const float2 s2 = *(const float2*)&sc[k * SCP + 4];
      const float2 s3 = *(const float2*)&sc[k * SCP + 6];
      acc[0] = fmaf(s0.x, vv, acc[0]);
      acc[1] = fmaf(s0.y, vv, acc[1]);
      acc[2] = fmaf(s1.x, vv, acc[2]);
      acc[3] = fmaf(s1.y, vv, acc[3]);
      acc[4] = fmaf(s2.x, vv, acc[4]);
      acc[5] = fmaf(s2.y, vv, acc[5]);
      acc[6] = fmaf(s3.x, vv, acc[6]);
      acc[7] = fmaf(s3.y, vv, acc[7]);
    }
#pragma unroll
    for (int t = 0; t < TT; ++t) red[(g * TT + t) * HD + d] = acc[t];
  }
  __syncthreads();

  // phase 4: cross-group reduce + normalize + store (row-major for out-proj)
  if (tid < TT * HD) {
    const int t = tid / HD, d = tid - (tid / HD) * HD;
    float a = 0.f;
#pragma unroll
    for (int g = 0; g < TT; ++g) a += red[(g * TT + t) * HD + d];
    out[((size_t)(bh >> 3) * TT + t) * DIM + (bh & 7) * HD + d] = f2bf(a * isum[t]);
  }
}

// ---------------- launch ----------------
extern "C" void kernel_launch(void* const* d_in, const int* in_sizes, int n_in,
                              void* d_out, int out_size, void* d_ws, size_t ws_size,
                              hipStream_t stream)
{
  const float* x   = (const float*)d_in[0];
  const float* h_a = (const float*)d_in[1];
  const float* h_t = (const float*)d_in[2];
  const float* p   = (const float*)d_in[3];
  const float* Wq  = (const float*)d_in[4];  const float* bq  = (const float*)d_in[5];
  const float* Wks = (const float*)d_in[6];  const float* bks = (const float*)d_in[7];
  const float* Wvs = (const float*)d_in[8];  const float* bvs = (const float*)d_in[9];
  const float* Wka = (const float*)d_in[10]; const float* bka = (const float*)d_in[11];
  const float* Wva = (const float*)d_in[12]; const float* bva = (const float*)d_in[13];
  const float* Wkt = (const float*)d_in[14]; const float* bkt = (const float*)d_in[15];
  const float* Wvt = (const float*)d_in[16]; const float* bvt = (const float*)d_in[17];
  const float* Wo  = (const float*)d_in[18]; const float* bo  = (const float*)d_in[19];
  const float* Wf  = (const float*)d_in[20]; const float* bf_ = (const float*)d_in[21];
  const float* gate = (const float*)d_in[22];
  const float* ln_g = (const float*)d_in[23];
  const float* ln_b = (const float*)d_in[24];

  // ---- workspace layout (bytes) ----
  const size_t SZ_HAD = (size_t)KAPAD * DIM * 2;            // bf16
  const size_t SZ_SM  = (size_t)BB * TT * DIM * 2;          // bf16 small [512 x 896]
  const size_t SZ_KV  = (size_t)BB * NH * NKEYS * HD * 2;   // bf16 [b][h][585][112]
  const size_t SZ_WT  = (size_t)9 * DD * 2;                 // 9 weights bf16
  const size_t needed = SZ_HAD + SZ_SM * 2 + SZ_KV * 2 + SZ_WT
                        + (size_t)BB * TT * DIM * 4;        // + yb fp32
  if (ws_size < needed) return;  // fail loud, not UB

  char* wsp = (char*)d_ws;
  short* hadb = (short*)wsp; wsp += SZ_HAD;
  short* qb   = (short*)wsp; wsp += SZ_SM;   // head-major [b][h][8][112]
  short* kall = (short*)wsp; wsp += SZ_KV;   // head-major [b][h][585][112]
  short* vall = (short*)wsp; wsp += SZ_KV;
  short* WtA  = (short*)wsp; wsp += SZ_WT;
  short* attn_outb = (short*)wsp; wsp += SZ_SM;
  float* yb   = (float*)wsp; wsp += (size_t)BB * TT * DIM * 4;

  dim3 blk(256);

  // 0) transpose all 9 weights -> bf16 [n][k], concatenated
  W9 w9; const float* Ws[9] = {Wq, Wks, Wvs, Wka, Wva, Wkt, Wvt, Wo, Wf};
  for (int i = 0; i < 9; ++i) w9.w[i] = Ws[i];
  wtrans<<<dim3(28, 28, 9), blk, 0, stream>>>(w9, WtA);

  // 1) h_ad -> bf16
  build_had<<<(KAPAD * DIM / 8 + 255) / 256, blk, 0, stream>>>(h_a, p, hadb);

  // 2) fused S-group GEMM: [q | k_s | v_s] = x(f32) @ [Wq|Wks|Wvs] (head-major out)
  {
    EpiCfg c = {};
    c.bias[0] = bq;  c.outB[0] = qb;   c.epi[0] = EPI_ROPE; c.pos_mod[0] = TT;
    c.hm[0] = 1; c.hm_L[0] = TT; c.hm_ltot[0] = TT;
    c.bias[1] = bks; c.outB[1] = kall; c.epi[1] = EPI_ROPE; c.pos_mod[1] = TT;
    c.hm[1] = 1; c.hm_L[1] = TT; c.hm_ltot[1] = NKEYS;
    c.bias[2] = bvs; c.outB[2] = vall; c.epi[2] = EPI_NONE; c.pos_mod[2] = 1;
    c.hm[2] = 1; c.hm_L[2] = TT; c.hm_ltot[2] = NKEYS;
    gemm_bf16<true><<<dim3(21, BB * TT / 128), blk, 0, stream>>>(nullptr, x, WtA, c);
  }
  // 3) fused A-group GEMM: [k_a | v_a] = hadb @ [Wka|Wva] (head-major, seg off 8)
  {
    EpiCfg c = {};
    c.bias[0] = bka; c.outB[0] = kall + (size_t)TT * HD; c.epi[0] = EPI_ROPE;
    c.pos_mod[0] = KA; c.hm[0] = 1; c.hm_L[0] = KA; c.hm_ltot[0] = NKEYS;
    c.bias[1] = bva; c.outB[1] = vall + (size_t)TT * HD; c.epi[1] = EPI_NONE;
    c.pos_mod[1] = 1; c.hm[1] = 1; c.hm_L[1] = KA; c.hm_ltot[1] = NKEYS;
    gemm_bf16<false><<<dim3(14, KAPAD / 128), blk, 0, stream>>>(
        hadb, nullptr, WtA + (size_t)3 * DD, c);
  }
  // 4) T-group GEMM, ONE launch, f32 A fused, XCD-swizzled (gridDim.y=256, %8==0)
  {
    EpiCfg c = {};
    c.bias[0] = bkt; c.outB[0] = kall + (size_t)(TT + KA) * HD; c.epi[0] = EPI_ROPE;
    c.pos_mod[0] = KT; c.hm[0] = 1; c.hm_L[0] = KT; c.hm_ltot[0] = NKEYS;
    c.bias[1] = bvt; c.outB[1] = vall + (size_t)(TT + KA) * HD; c.epi[1] = EPI_NONE;
    c.pos_mod[1] = 1; c.hm[1] = 1; c.hm_L[1] = KT; c.hm_ltot[1] = NKEYS;
    c.row_off = 0;
    c.swz = 1;
    gemm_bf16<true><<<dim3(14, BB * KT / 128), blk, 0, stream>>>(
        nullptr, h_t, WtA + (size_t)5 * DD, c);
  }

  // 5) attention — proven kernel, 1024 threads/block
  attn_kernel<<<BB * NH, dim3(1024), 0, stream>>>(qb, kall, vall, gate, attn_outb);

  // 6) out-proj + residual (fp32 out)
  {
    EpiCfg c = {};
    c.bias[0] = bo; c.outF[0] = yb; c.epi[0] = EPI_RESID; c.pos_mod[0] = 1;
    c.resid = x;
    gemm_bf16<false><<<dim3(7, BB * TT / 128), blk, 0, stream>>>(
        attn_outb, nullptr, WtA + (size_t)7 * DD, c);
  }
  // 7) FFN with fused LayerNorm + ReLU (fp32 d_out)
  {
    EpiCfg c = {};
    c.bias[0] = bf_; c.outF[0] = (float*)d_out; c.epi[0] = EPI_RELU; c.pos_mod[0] = 1;
    gemm_ffn<<<dim3(7, BB * TT / 128), blk, 0, stream>>>(
        yb, ln_g, ln_b, WtA + (size_t)8 * DD, c);
  }
}

// Round 9
// 695.882 us; speedup vs baseline: 1.2698x; 1.0865x over previous
//
#include <hip/hip_runtime.h>
#include <hip/hip_bf16.h>
#include <math.h>

#define DIM 896
#define DD  (DIM * DIM)
#define NH 8
#define HD 112
#define BB 64
#define TT 8
#define KA 65
#define KAPAD 4224   // 64*65 = 4160 padded to 33*128
#define KT 512
#define NKEYS (TT + KA + KT)   // 585

#define EPI_NONE  0
#define EPI_ROPE  1
#define EPI_RESID 2
#define EPI_RELU  3

// -log2(10000)/56
#define NEG_L2_10K_OVER_56 (-0.2373327285062406f)

#ifndef __has_builtin
#define __has_builtin(x) 0
#endif
#if __has_builtin(__builtin_amdgcn_global_load_lds)
#define HAS_GLL 1
#else
#define HAS_GLL 0
#endif

typedef __attribute__((ext_vector_type(8))) short bf16x8_t;   // 8 bf16 (4 VGPRs)
typedef __attribute__((ext_vector_type(4))) float f32x4_t;    // MFMA accumulator

__device__ __forceinline__ short f2bf(float f) {
  unsigned u = __float_as_uint(f);
  u += 0x7fffu + ((u >> 16) & 1u);
  return (short)(u >> 16);
}
__device__ __forceinline__ float bf2f(short s) {
  return __uint_as_float(((unsigned)(unsigned short)s) << 16);
}
// 2x f32 -> packed bf16 pair (RNE; bit-identical to f2bf for normals).
__device__ __forceinline__ unsigned cvt_pk_bf16(float lo, float hi) {
  unsigned r;
  asm("v_cvt_pk_bf16_f32 %0, %1, %2" : "=v"(r) : "v"(lo), "v"(hi));
  return r;
}
// 16-B global -> LDS direct copy. dest = lbase + lane*16B (wave-uniform base).
__device__ __forceinline__ void gll16(const short* g, short* lbase, int lane) {
#if HAS_GLL
  __builtin_amdgcn_global_load_lds(
      (const __attribute__((address_space(1))) unsigned*)g,
      (__attribute__((address_space(3))) unsigned*)lbase, 16, 0, 0);
#else
  *(bf16x8_t*)(lbase + lane * 8) = *(const bf16x8_t*)g;
#endif
}

// ---------------- 9-way weight transpose: W[k][n] f32 -> Wt[n][k] bf16 ----------------
struct W9 { const float* w[9]; };

__global__ __launch_bounds__(256) void wtrans(W9 ws, short* __restrict__ Wt)
{
  __shared__ float t[32][33];
  const float* W = ws.w[blockIdx.z];
  short* dst = Wt + (size_t)blockIdx.z * DD;
  const int bx = blockIdx.x, by = blockIdx.y;
  const int tx = threadIdx.x & 31, ty = threadIdx.x >> 5;
#pragma unroll
  for (int i = 0; i < 4; ++i)
    t[ty + i * 8][tx] = W[(size_t)(by * 32 + ty + i * 8) * DIM + bx * 32 + tx];
  __syncthreads();
#pragma unroll
  for (int i = 0; i < 4; ++i)
    dst[(size_t)(bx * 32 + ty + i * 8) * DIM + by * 32 + tx] = f2bf(t[tx][ty + i * 8]);
}

// ---------------- h_ad = concat(h_a, p) -> bf16, zero-padded to 4224 rows ----------------
__global__ __launch_bounds__(256) void build_had(
    const float* __restrict__ h_a, const float* __restrict__ p,
    short* __restrict__ had)
{
  const int i = blockIdx.x * 256 + threadIdx.x;  // one per 8 elements
  const int total = KAPAD * DIM / 8;
  if (i >= total) return;
  const int c = (i % 112) * 8;
  const int row = i / 112;
  bf16x8_t o;
  if (row >= BB * KA) {
#pragma unroll
    for (int j = 0; j < 8; ++j) o[j] = 0;
  } else {
    const int b = row / KA, j = row % KA;
    const float* src = (j < KA - 1) ? h_a + ((size_t)b * (KA - 1) + j) * DIM + c
                                    : p + (size_t)b * DIM + c;
    const float4 a = *(const float4*)src;
    const float4 d = *(const float4*)(src + 4);
    o[0] = f2bf(a.x); o[1] = f2bf(a.y); o[2] = f2bf(a.z); o[3] = f2bf(a.w);
    o[4] = f2bf(d.x); o[5] = f2bf(d.y); o[6] = f2bf(d.z); o[7] = f2bf(d.w);
  }
  ((bf16x8_t*)had)[i] = o;
}

// ---------------- MFMA GEMM core: BK=64 single-buffer + XOR-swizzled LDS ----------
// C[128 x 128] tile of A[M x 896] @ Wt[N x 896](n-major) + bias.
// K-loop identical to round-8 (proven: bank-conflicts = 0).
// NEW epilogue (hm path): results staged through a 128x128 bf16 C-tile in LDS
// (aliased onto As+Bs, exactly 32 KB) with granule-XOR layout
// phys_g = g ^ (((row>>2)&3)<<1)  -> write pass 2 lanes/bank (free), read pass
// bijective full-row (free). Then 8 coalesced 16-B global stores per thread
// (head boundary 112 ≡ 0 mod 8 -> a 8-col chunk never straddles heads).
struct EpiCfg {
  const float* bias[3];
  float* outF[3];
  short* outB[3];
  const float* resid;
  int epi[3];
  int pos_mod[3];
  int row_off;
  int hm[3];       // head-major store flag
  int hm_L[3];     // rows per batch (grow decode)
  int hm_ltot[3];  // row stride per (b,h) in the destination
  int swz;         // XCD swizzle on/off (T-GEMM)
};

template <bool AF32, bool DOLN>
__device__ __forceinline__ void gemm_body(
    short* As, short* Bs,
    const short* A, const float* Af, const short* Wt,
    const EpiCfg& cfg, int bx, int by,
    const float* smu, const float* srs,
    const float* lngam, const float* lnbet)
{
  const int tid = threadIdx.x;
  const int wave = tid >> 6, lane = tid & 63;
  const int sub = bx / 7;
  const int col0 = (bx % 7) * 128;
  const int row0 = by * 128;
  const int wm = wave >> 1, wn = wave & 1;
  const int lm = lane & 15, lq = lane >> 4;

  // gll16 staging: one call = 8 rows x 128 B. lane -> row-in-8 = lane>>3,
  // physical granule = lane&7, so load logical granule (lane&7)^(row&7).
  const int sr = lane >> 3;
  const int sg = (lane & 7) ^ sr;          // pre-swizzled source granule
  const short* Wg = Wt + (size_t)(sub * DIM + col0 + wave * 32 + sr) * DIM + sg * 8;
  const short* Ag = nullptr;
  if constexpr (!AF32)
    Ag = A + (size_t)(row0 + wave * 32 + sr) * DIM + sg * 8;

  f32x4_t acc[4][4];
#pragma unroll
  for (int i = 0; i < 4; ++i)
#pragma unroll
    for (int j = 0; j < 4; ++j) acc[i][j] = (f32x4_t){0.f, 0.f, 0.f, 0.f};

  for (int k0 = 0; k0 < DIM; k0 += 64) {
    __syncthreads();
    if constexpr (AF32) {
      // 4 chunks/thread: chunk c = tid + 256*j -> row = c>>3, logical granule g = c&7
#pragma unroll
      for (int j = 0; j < 4; ++j) {
        const int c = tid + 256 * j;
        const int row = c >> 3, g = c & 7;
        const float* srcp = Af + (size_t)(row0 + row) * DIM + k0 + g * 8;
        const float4 a0 = *(const float4*)srcp;
        const float4 a1 = *(const float4*)(srcp + 4);
        float e[8] = {a0.x, a0.y, a0.z, a0.w, a1.x, a1.y, a1.z, a1.w};
        if constexpr (DOLN) {
          const float mu = smu[row], rs = srs[row];
#pragma unroll
          for (int q = 0; q < 8; ++q) {
            const int k = k0 + g * 8 + q;
            e[q] = (e[q] - mu) * rs * lngam[k] + lnbet[k];
          }
        }
        uint4 w;
        w.x = cvt_pk_bf16(e[0], e[1]); w.y = cvt_pk_bf16(e[2], e[3]);
        w.z = cvt_pk_bf16(e[4], e[5]); w.w = cvt_pk_bf16(e[6], e[7]);
        *(uint4*)&As[row * 64 + ((g ^ (row & 7)) << 3)] = w;
      }
    } else {
#pragma unroll
      for (int j = 0; j < 4; ++j)
        gll16(Ag + (size_t)(j * 8) * DIM + k0, &As[(wave * 32 + j * 8) * 64], lane);
    }
#pragma unroll
    for (int j = 0; j < 4; ++j)
      gll16(Wg + (size_t)(j * 8) * DIM + k0, &Bs[(wave * 32 + j * 8) * 64], lane);
    __syncthreads();

    bf16x8_t afr[4][2], bfr[4][2];
#pragma unroll
    for (int t = 0; t < 4; ++t) {
      const int ra = wm * 64 + t * 16 + lm;
      const int rb = wn * 64 + t * 16 + lm;
      afr[t][0] = *(const bf16x8_t*)&As[ra * 64 + (((lq) ^ (ra & 7)) << 3)];
      afr[t][1] = *(const bf16x8_t*)&As[ra * 64 + (((4 + lq) ^ (ra & 7)) << 3)];
      bfr[t][0] = *(const bf16x8_t*)&Bs[rb * 64 + (((lq) ^ (rb & 7)) << 3)];
      bfr[t][1] = *(const bf16x8_t*)&Bs[rb * 64 + (((4 + lq) ^ (rb & 7)) << 3)];
    }
#pragma unroll
    for (int kk = 0; kk < 2; ++kk)
#pragma unroll
      for (int tm = 0; tm < 4; ++tm)
#pragma unroll
        for (int tn = 0; tn < 4; ++tn)
          acc[tm][tn] = __builtin_amdgcn_mfma_f32_16x16x32_bf16(
              afr[tm][kk], bfr[tn][kk], acc[tm][tn], 0, 0, 0);
  }

  // epilogue — C/D frag: row = lq*4 + reg, col = lm (per 16x16 tile)
  const float* bias = cfg.bias[sub];
  float* outF = cfg.outF[sub];
  short* outB = cfg.outB[sub];
  const int epi = cfg.epi[sub], pm = cfg.pos_mod[sub];
  const int hm = cfg.hm[sub];
  const int L = cfg.hm_L[sub], ltot = cfg.hm_ltot[sub];

  if (hm) {
    // rope position per (tm, r): l within L
    int gl[4][4];
#pragma unroll
    for (int tm = 0; tm < 4; ++tm) {
      const int g = cfg.row_off + row0 + wm * 64 + tm * 16 + lq * 4;
      int bq2 = g / L;
      int l = g - bq2 * L;
#pragma unroll
      for (int r = 0; r < 4; ++r) {
        gl[tm][r] = l;
        if (++l == L) { l = 0; ++bq2; }
      }
    }
    short* Cs = As;           // alias: As+Bs = 32 KB = 128x128 bf16 C-tile
    __syncthreads();          // all frag reads of As/Bs complete
    // pass 1: bias + rope, write to swizzled LDS C-tile (conflict-free)
#pragma unroll
    for (int tn = 0; tn < 4; ++tn) {
      const int lc = wn * 64 + tn * 16 + lm;
      const int col = col0 + lc;
      const float bv = bias[col];
      float fr = 0.f, sgn = 0.f;
      if (epi == EPI_ROPE) {
        const int d0 = col % HD;
        fr = exp2f((float)(d0 % 56) * NEG_L2_10K_OVER_56);
        sgn = (d0 & 1) ? 1.f : -1.f;
      }
#pragma unroll
      for (int tm = 0; tm < 4; ++tm) {
#pragma unroll
        for (int r = 0; r < 4; ++r) {
          float v = acc[tm][tn][r] + bv;
          if (epi == EPI_ROPE) {
            const float prt = __shfl_xor(v, 1);   // partner col (lane^1), pre-rope
            float s, c;
            __sincosf((float)gl[tm][r] * fr, &s, &c);
            v = v * c + sgn * prt * s;
          }
          const int lr = wm * 64 + tm * 16 + lq * 4 + r;
          const int gp = (lc >> 3) ^ (((lr >> 2) & 3) << 1);
          Cs[lr * 128 + gp * 8 + (lc & 7)] = f2bf(v);
        }
      }
    }
    __syncthreads();
    // pass 2: 8 coalesced 16-B stores per thread
#pragma unroll
    for (int i = 0; i < 8; ++i) {
      const int ch = tid + 256 * i;
      const int lr = ch >> 4, g = ch & 15;
      const int phys = g ^ (((lr >> 2) & 3) << 1);
      const bf16x8_t val = *(const bf16x8_t*)&Cs[lr * 128 + phys * 8];
      const int grow = cfg.row_off + row0 + lr;
      const int bq2 = grow / L;
      const int l = grow - bq2 * L;
      const int col = col0 + g * 8;
      const int h = col / HD, d = col - h * HD;
      if (bq2 < BB)
        *(bf16x8_t*)&outB[((size_t)(bq2 * NH + h) * ltot + l) * HD + d] = val;
    }
    return;
  }

  // non-hm path (outF f32: out-proj RESID, FFN RELU) — unchanged scalar epilogue
#pragma unroll
  for (int tn = 0; tn < 4; ++tn) {
    const int col = col0 + wn * 64 + tn * 16 + lm;
    const float bv = bias[col];
#pragma unroll
    for (int tm = 0; tm < 4; ++tm) {
#pragma unroll
      for (int r = 0; r < 4; ++r) {
        const int grow = cfg.row_off + row0 + wm * 64 + tm * 16 + lq * 4 + r;
        float v = acc[tm][tn][r] + bv;
        if (epi == EPI_RESID) {
          v += cfg.resid[(size_t)grow * DIM + col];
        } else if (epi == EPI_RELU) {
          v = fmaxf(v, 0.f);
        }
        if (outB) outB[(size_t)grow * DIM + col] = f2bf(v);
        else      outF[(size_t)grow * DIM + col] = v;
      }
    }
  }
}

// ---------------- GEMM kernels (separate launches — r5/r8 proven structure) --------
template <bool AF32>
__global__ __launch_bounds__(256) void gemm_bf16(
    const short* __restrict__ A, const float* __restrict__ Af,
    const short* __restrict__ Wt, EpiCfg cfg)
{
  __shared__ __align__(16) short lds[2 * 128 * 64];
  int bx = blockIdx.x, by = blockIdx.y;
  if (cfg.swz) {
    const int nx = gridDim.x;
    const int bid = blockIdx.x + blockIdx.y * nx;   // HW dispatch order
    const int xcd = bid & 7, ixd = bid >> 3;
    const int rpx = gridDim.y >> 3;                 // row panels per XCD
    bx = ixd % nx;
    by = xcd * rpx + ixd / nx;
  }
  gemm_body<AF32, false>(lds, lds + 128 * 64, A, Af, Wt, cfg, bx, by,
                         nullptr, nullptr, nullptr, nullptr);
}

// FFN GEMM with fused LayerNorm on the A-staging (A = LN(y); K range == LN row).
__global__ __launch_bounds__(256) void gemm_ffn(
    const float* __restrict__ Y, const float* __restrict__ lng,
    const float* __restrict__ lnb, const short* __restrict__ Wt, EpiCfg cfg)
{
  __shared__ __align__(16) short lds[2 * 128 * 64];
  __shared__ float glds[DIM], blds[DIM];
  __shared__ float smu[128], srs[128];
  const int tid = threadIdx.x;
  const int row0 = blockIdx.y * 128;
  for (int i = tid; i < DIM; i += 256) { glds[i] = lng[i]; blds[i] = lnb[i]; }
  {
    const int r = tid >> 1, h = tid & 1;   // 2 threads per row, 448 elems each
    const float* rp = Y + (size_t)(row0 + r) * DIM + h * 448;
    float s = 0.f, q = 0.f;
    for (int i = 0; i < 448; i += 4) {
      const float4 v = *(const float4*)(rp + i);
      s += v.x + v.y + v.z + v.w;
      q = fmaf(v.x, v.x, fmaf(v.y, v.y, fmaf(v.z, v.z, fmaf(v.w, v.w, q))));
    }
    s += __shfl_xor(s, 1);
    q += __shfl_xor(q, 1);
    if (h == 0) {
      const float mu = s * (1.f / DIM);
      const float var = q * (1.f / DIM) - mu * mu;
      smu[r] = mu;
      srs[r] = 1.f / sqrtf(var + 1e-5f);
    }
  }
  __syncthreads();
  gemm_body<true, true>(lds, lds + 128 * 64, nullptr, Y, Wt, cfg,
                        blockIdx.x, blockIdx.y, smu, srs, glds, blds);
}

// ---------------- attention: one 1024-thread block per (b,h) (round-1 proven) -------
#define SCP 10   // score row stride (floats): conflict-free (gcd(10,32)=2), float2-aligned

__global__ __launch_bounds__(1024, 8) void attn_kernel(
    const short* __restrict__ q, const short* __restrict__ kall,
    const short* __restrict__ vall, const float* __restrict__ gate,
    short* __restrict__ out)
{
  __shared__ __align__(16) float qs[TT * HD];        // 3584 B
  __shared__ __align__(16) float sc[NKEYS * SCP];    // 23400 B, [k][t] padded
  __shared__ float red[TT * TT * HD];                // 28672 B, [g][t][d]
  __shared__ float isum[TT];
  const int tid = threadIdx.x;
  const int bh = blockIdx.x;
  const float scale = 0.09449111825230681f;  // 1/sqrt(112)
  const float rg = tanhf(gate[0]);

  // phase 0: q -> fp32 LDS (contiguous head-major load)
  if (tid < TT * HD) qs[tid] = bf2f(q[(size_t)bh * (TT * HD) + tid]);
  __syncthreads();

  // phase 1: scores — one thread per key, contiguous 224 B key row
  if (tid < NKEYS) {
    const int k = tid;
    const short* kp = kall + ((size_t)bh * NKEYS + k) * HD;
    float dot[TT] = {};
    for (int d8 = 0; d8 < HD; d8 += 8) {
      const bf16x8_t kv8 = *(const bf16x8_t*)(kp + d8);
      float kf[8];
#pragma unroll
      for (int j = 0; j < 8; ++j) kf[j] = bf2f(kv8[j]);
#pragma unroll
      for (int t = 0; t < TT; ++t) {
        const float4 qa = *(const float4*)&qs[t * HD + d8];
        const float4 qb4 = *(const float4*)&qs[t * HD + d8 + 4];
        dot[t] = fmaf(qa.x, kf[0], dot[t]);
        dot[t] = fmaf(qa.y, kf[1], dot[t]);
        dot[t] = fmaf(qa.z, kf[2], dot[t]);
        dot[t] = fmaf(qa.w, kf[3], dot[t]);
        dot[t] = fmaf(qb4.x, kf[4], dot[t]);
        dot[t] = fmaf(qb4.y, kf[5], dot[t]);
        dot[t] = fmaf(qb4.z, kf[6], dot[t]);
        dot[t] = fmaf(qb4.w, kf[7], dot[t]);
      }
    }
    const float s = (k >= TT + KA) ? scale * rg : scale;
#pragma unroll
    for (int t = 0; t < TT; ++t) sc[k * SCP + t] = dot[t] * s;
  }
  __syncthreads();

  // phase 2: softmax per t-row, one wave per row
  const int wave = tid >> 6, lane = tid & 63;
  if (wave < TT) {
    const int t = wave;
    float m = -1e30f;
    for (int k = lane; k < NKEYS; k += 64) m = fmaxf(m, sc[k * SCP + t]);
#pragma unroll
    for (int o = 32; o >= 1; o >>= 1) m = fmaxf(m, __shfl_xor(m, o));
    float sum = 0.f;
    for (int k = lane; k < NKEYS; k += 64) {
      const float e = expf(sc[k * SCP + t] - m);
      sc[k * SCP + t] = e;
      sum += e;
    }
#pragma unroll
    for (int o = 32; o >= 1; o >>= 1) sum += __shfl_xor(sum, o);
    if (lane == 0) isum[t] = 1.f / sum;
  }
  __syncthreads();

  // phase 3: PV partials — keys split 8 ways, each thread owns (group g, dim d)
  if (tid < TT * HD) {
    const int g = tid / HD, d = tid - (tid / HD) * HD;
    const int kb = (g * NKEYS) / TT, ke = ((g + 1) * NKEYS) / TT;
    const short* vp = vall + (size_t)bh * (NKEYS * HD) + d;
    float acc[TT] = {};
    for (int k = kb; k < ke; ++k) {
      const float vv = bf2f(vp[(size_t)k * HD]);
      const float2 s0 = *(const float2*)&sc[k * SCP];
      const float2 s1 = *(const float2*)&sc[k * SCP + 2];
      const float2 s2 = *(const float2*)&sc[k * SCP + 4];
      const float2 s3 = *(const float2*)&sc[k * SCP + 6];
      acc[0] = fmaf(s0.x, vv, acc[0]);
      acc[1] = fmaf(s0.y, vv, acc[1]);
      acc[2] = fmaf(s1.x, vv, acc[2]);
      acc[3] = fmaf(s1.y, vv, acc[3]);
      acc[4] = fmaf(s2.x, vv, acc[4]);
      acc[5] = fmaf(s2.y, vv, acc[5]);
      acc[6] = fmaf(s3.x, vv, acc[6]);
      acc[7] = fmaf(s3.y, vv, acc[7]);
    }
#pragma unroll
    for (int t = 0; t < TT; ++t) red[(g * TT + t) * HD + d] = acc[t];
  }
  __syncthreads();

  // phase 4: cross-group reduce + normalize + store (row-major for out-proj)
  if (tid < TT * HD) {
    const int t = tid / HD, d = tid - (tid / HD) * HD;
    float a = 0.f;
#pragma unroll
    for (int g = 0; g < TT; ++g) a += red[(g * TT + t) * HD + d];
    out[((size_t)(bh >> 3) * TT + t) * DIM + (bh & 7) * HD + d] = f2bf(a * isum[t]);
  }
}

// ---------------- launch ----------------
extern "C" void kernel_launch(void* const* d_in, const int* in_sizes, int n_in,
                              void* d_out, int out_size, void* d_ws, size_t ws_size,
                              hipStream_t stream)
{
  const float* x   = (const float*)d_in[0];
  const float* h_a = (const float*)d_in[1];
  const float* h_t = (const float*)d_in[2];
  const float* p   = (const float*)d_in[3];
  const float* Wq  = (const float*)d_in[4];  const float* bq  = (const float*)d_in[5];
  const float* Wks = (const float*)d_in[6];  const float* bks = (const float*)d_in[7];
  const float* Wvs = (const float*)d_in[8];  const float* bvs = (const float*)d_in[9];
  const float* Wka = (const float*)d_in[10]; const float* bka = (const float*)d_in[11];
  const float* Wva = (const float*)d_in[12]; const float* bva = (const float*)d_in[13];
  const float* Wkt = (const float*)d_in[14]; const float* bkt = (const float*)d_in[15];
  const float* Wvt = (const float*)d_in[16]; const float* bvt = (const float*)d_in[17];
  const float* Wo  = (const float*)d_in[18]; const float* bo  = (const float*)d_in[19];
  const float* Wf  = (const float*)d_in[20]; const float* bf_ = (const float*)d_in[21];
  const float* gate = (const float*)d_in[22];
  const float* ln_g = (const float*)d_in[23];
  const float* ln_b = (const float*)d_in[24];

  // ---- workspace layout (bytes) ----
  const size_t SZ_HAD = (size_t)KAPAD * DIM * 2;            // bf16
  const size_t SZ_SM  = (size_t)BB * TT * DIM * 2;          // bf16 small [512 x 896]
  const size_t SZ_KV  = (size_t)BB * NH * NKEYS * HD * 2;   // bf16 [b][h][585][112]
  const size_t SZ_WT  = (size_t)9 * DD * 2;                 // 9 weights bf16
  const size_t needed = SZ_HAD + SZ_SM * 2 + SZ_KV * 2 + SZ_WT
                        + (size_t)BB * TT * DIM * 4;        // + yb fp32
  if (ws_size < needed) return;  // fail loud, not UB

  char* wsp = (char*)d_ws;
  short* hadb = (short*)wsp; wsp += SZ_HAD;
  short* qb   = (short*)wsp; wsp += SZ_SM;   // head-major [b][h][8][112]
  short* kall = (short*)wsp; wsp += SZ_KV;   // head-major [b][h][585][112]
  short* vall = (short*)wsp; wsp += SZ_KV;
  short* WtA  = (short*)wsp; wsp += SZ_WT;
  short* attn_outb = (short*)wsp; wsp += SZ_SM;
  float* yb   = (float*)wsp; wsp += (size_t)BB * TT * DIM * 4;

  dim3 blk(256);

  // 0) transpose all 9 weights -> bf16 [n][k], concatenated
  W9 w9; const float* Ws[9] = {Wq, Wks, Wvs, Wka, Wva, Wkt, Wvt, Wo, Wf};
  for (int i = 0; i < 9; ++i) w9.w[i] = Ws[i];
  wtrans<<<dim3(28, 28, 9), blk, 0, stream>>>(w9, WtA);

  // 1) h_ad -> bf16
  build_had<<<(KAPAD * DIM / 8 + 255) / 256, blk, 0, stream>>>(h_a, p, hadb);

  // 2) fused S-group GEMM: [q | k_s | v_s] = x(f32) @ [Wq|Wks|Wvs] (head-major out)
  {
    EpiCfg c = {};
    c.bias[0] = bq;  c.outB[0] = qb;   c.epi[0] = EPI_ROPE; c.pos_mod[0] = TT;
    c.hm[0] = 1; c.hm_L[0] = TT; c.hm_ltot[0] = TT;
    c.bias[1] = bks; c.outB[1] = kall; c.epi[1] = EPI_ROPE; c.pos_mod[1] = TT;
    c.hm[1] = 1; c.hm_L[1] = TT; c.hm_ltot[1] = NKEYS;
    c.bias[2] = bvs; c.outB[2] = vall; c.epi[2] = EPI_NONE; c.pos_mod[2] = 1;
    c.hm[2] = 1; c.hm_L[2] = TT; c.hm_ltot[2] = NKEYS;
    gemm_bf16<true><<<dim3(21, BB * TT / 128), blk, 0, stream>>>(nullptr, x, WtA, c);
  }
  // 3) fused A-group GEMM: [k_a | v_a] = hadb @ [Wka|Wva] (head-major, seg off 8)
  {
    EpiCfg c = {};
    c.bias[0] = bka; c.outB[0] = kall + (size_t)TT * HD; c.epi[0] = EPI_ROPE;
    c.pos_mod[0] = KA; c.hm[0] = 1; c.hm_L[0] = KA; c.hm_ltot[0] = NKEYS;
    c.bias[1] = bva; c.outB[1] = vall + (size_t)TT * HD; c.epi[1] = EPI_NONE;
    c.pos_mod[1] = 1; c.hm[1] = 1; c.hm_L[1] = KA; c.hm_ltot[1] = NKEYS;
    gemm_bf16<false><<<dim3(14, KAPAD / 128), blk, 0, stream>>>(
        hadb, nullptr, WtA + (size_t)3 * DD, c);
  }
  // 4) T-group GEMM, ONE launch, f32 A fused, XCD-swizzled (gridDim.y=256, %8==0)
  {
    EpiCfg c = {};
    c.bias[0] = bkt; c.outB[0] = kall + (size_t)(TT + KA) * HD; c.epi[0] = EPI_ROPE;
    c.pos_mod[0] = KT; c.hm[0] = 1; c.hm_L[0] = KT; c.hm_ltot[0] = NKEYS;
    c.bias[1] = bvt; c.outB[1] = vall + (size_t)(TT + KA) * HD; c.epi[1] = EPI_NONE;
    c.pos_mod[1] = 1; c.hm[1] = 1; c.hm_L[1] = KT; c.hm_ltot[1] = NKEYS;
    c.row_off = 0;
    c.swz = 1;
    gemm_bf16<true><<<dim3(14, BB * KT / 128), blk, 0, stream>>>(
        nullptr, h_t, WtA + (size_t)5 * DD, c);
  }

  // 5) attention — proven kernel, 1024 threads/block
  attn_kernel<<<BB * NH, dim3(1024), 0, stream>>>(qb, kall, vall, gate, attn_outb);

  // 6) out-proj + residual (fp32 out)
  {
    EpiCfg c = {};
    c.bias[0] = bo; c.outF[0] = yb; c.epi[0] = EPI_RESID; c.pos_mod[0] = 1;
    c.resid = x;
    gemm_bf16<false><<<dim3(7, BB * TT / 128), blk, 0, stream>>>(
        attn_outb, nullptr, WtA + (size_t)7 * DD, c);
  }
  // 7) FFN with fused LayerNorm + ReLU (fp32 d_out)
  {
    EpiCfg c = {};
    c.bias[0] = bf_; c.outF[0] = (float*)d_out; c.epi[0] = EPI_RELU; c.pos_mod[0] = 1;
    gemm_ffn<<<dim3(7, BB * TT / 128), blk, 0, stream>>>(
        yb, ln_g, ln_b, WtA + (size_t)8 * DD, c);
  }
}

// Round 11
// 643.701 us; speedup vs baseline: 1.3727x; 1.0811x over previous
//
#include <hip/hip_runtime.h>
#include <hip/hip_bf16.h>
#include <math.h>

#define DIM 896
#define DD  (DIM * DIM)
#define NH 8
#define HD 112
#define BB 64
#define TT 8
#define KA 65
#define KAPAD 4224   // 64*65 = 4160 padded to 33*128
#define KT 512
#define NKEYS (TT + KA + KT)   // 585

#define EPI_NONE  0
#define EPI_ROPE  1
#define EPI_RESID 2
#define EPI_RELU  3

// -log2(10000)/56
#define NEG_L2_10K_OVER_56 (-0.2373327285062406f)

#ifndef __has_builtin
#define __has_builtin(x) 0
#endif
#if __has_builtin(__builtin_amdgcn_global_load_lds)
#define HAS_GLL 1
#else
#define HAS_GLL 0
#endif

typedef __attribute__((ext_vector_type(8))) short bf16x8_t;   // 8 bf16 (4 VGPRs)
typedef __attribute__((ext_vector_type(4))) float f32x4_t;    // MFMA accumulator

__device__ __forceinline__ short f2bf(float f) {
  unsigned u = __float_as_uint(f);
  u += 0x7fffu + ((u >> 16) & 1u);
  return (short)(u >> 16);
}
__device__ __forceinline__ float bf2f(short s) {
  return __uint_as_float(((unsigned)(unsigned short)s) << 16);
}
// 2x f32 -> packed bf16 pair (RNE; bit-identical to f2bf for normals).
__device__ __forceinline__ unsigned cvt_pk_bf16(float lo, float hi) {
  unsigned r;
  asm("v_cvt_pk_bf16_f32 %0, %1, %2" : "=v"(r) : "v"(lo), "v"(hi));
  return r;
}
// 16-B global -> LDS direct copy. dest = lbase + lane*16B (wave-uniform base).
__device__ __forceinline__ void gll16(const short* g, short* lbase, int lane) {
#if HAS_GLL
  __builtin_amdgcn_global_load_lds(
      (const __attribute__((address_space(1))) unsigned*)g,
      (__attribute__((address_space(3))) unsigned*)lbase, 16, 0, 0);
#else
  *(bf16x8_t*)(lbase + lane * 8) = *(const bf16x8_t*)g;
#endif
}

// ---------------- 9-way weight transpose: W[k][n] f32 -> Wt[n][k] bf16 ----------------
struct W9 { const float* w[9]; };

__global__ __launch_bounds__(256) void wtrans(W9 ws, short* __restrict__ Wt)
{
  __shared__ float t[32][33];
  const float* W = ws.w[blockIdx.z];
  short* dst = Wt + (size_t)blockIdx.z * DD;
  const int bx = blockIdx.x, by = blockIdx.y;
  const int tx = threadIdx.x & 31, ty = threadIdx.x >> 5;
#pragma unroll
  for (int i = 0; i < 4; ++i)
    t[ty + i * 8][tx] = W[(size_t)(by * 32 + ty + i * 8) * DIM + bx * 32 + tx];
  __syncthreads();
#pragma unroll
  for (int i = 0; i < 4; ++i)
    dst[(size_t)(bx * 32 + ty + i * 8) * DIM + by * 32 + tx] = f2bf(t[tx][ty + i * 8]);
}

// ---------------- h_ad = concat(h_a, p) -> bf16, zero-padded to 4224 rows ----------------
__global__ __launch_bounds__(256) void build_had(
    const float* __restrict__ h_a, const float* __restrict__ p,
    short* __restrict__ had)
{
  const int i = blockIdx.x * 256 + threadIdx.x;  // one per 8 elements
  const int total = KAPAD * DIM / 8;
  if (i >= total) return;
  const int c = (i % 112) * 8;
  const int row = i / 112;
  bf16x8_t o;
  if (row >= BB * KA) {
#pragma unroll
    for (int j = 0; j < 8; ++j) o[j] = 0;
  } else {
    const int b = row / KA, j = row % KA;
    const float* src = (j < KA - 1) ? h_a + ((size_t)b * (KA - 1) + j) * DIM + c
                                    : p + (size_t)b * DIM + c;
    const float4 a = *(const float4*)src;
    const float4 d = *(const float4*)(src + 4);
    o[0] = f2bf(a.x); o[1] = f2bf(a.y); o[2] = f2bf(a.z); o[3] = f2bf(a.w);
    o[4] = f2bf(d.x); o[5] = f2bf(d.y); o[6] = f2bf(d.z); o[7] = f2bf(d.w);
  }
  ((bf16x8_t*)had)[i] = o;
}

// ---------------- shared epilogue config ----------------
struct EpiCfg {
  const float* bias[3];
  float* outF[3];
  short* outB[3];
  const float* resid;
  int epi[3];
  int pos_mod[3];
  int row_off;
  int hm[3];       // head-major store flag
  int hm_L[3];     // rows per batch (grow decode)
  int hm_ltot[3];  // row stride per (b,h) in the destination
  int swz;         // XCD swizzle on/off
};

// r9-proven frag-read + MFMA step (swizzled [row][64] LDS, conflict-free).
__device__ __forceinline__ void compute_step(
    const short* As, const short* Bs, f32x4_t (&acc)[4][4],
    int wm, int wn, int lm, int lq)
{
  bf16x8_t afr[4][2], bfr[4][2];
#pragma unroll
  for (int t = 0; t < 4; ++t) {
    const int ra = wm * 64 + t * 16 + lm;
    const int rb = wn * 64 + t * 16 + lm;
    afr[t][0] = *(const bf16x8_t*)&As[ra * 64 + (((lq) ^ (ra & 7)) << 3)];
    afr[t][1] = *(const bf16x8_t*)&As[ra * 64 + (((4 + lq) ^ (ra & 7)) << 3)];
    bfr[t][0] = *(const bf16x8_t*)&Bs[rb * 64 + (((lq) ^ (rb & 7)) << 3)];
    bfr[t][1] = *(const bf16x8_t*)&Bs[rb * 64 + (((4 + lq) ^ (rb & 7)) << 3)];
  }
#pragma unroll
  for (int kk = 0; kk < 2; ++kk)
#pragma unroll
    for (int tm = 0; tm < 4; ++tm)
#pragma unroll
      for (int tn = 0; tn < 4; ++tn)
        acc[tm][tn] = __builtin_amdgcn_mfma_f32_16x16x32_bf16(
            afr[tm][kk], bfr[tn][kk], acc[tm][tn], 0, 0, 0);
}

// r9-proven hm epilogue: bias+rope -> swizzled LDS C-tile -> 8x coalesced 16-B stores.
__device__ __forceinline__ void epilogue_hm(
    short* Cs, f32x4_t (&acc)[4][4], const EpiCfg& cfg,
    int bx, int by, int wm, int wn, int lm, int lq, int tid)
{
  const int sub = bx / 7;
  const int col0 = (bx % 7) * 128;
  const int row0 = by * 128;
  const float* bias = cfg.bias[sub];
  short* outB = cfg.outB[sub];
  const int epi = cfg.epi[sub];
  const int L = cfg.hm_L[sub], ltot = cfg.hm_ltot[sub];
  int gl[4][4];
#pragma unroll
  for (int tm = 0; tm < 4; ++tm) {
    const int g = cfg.row_off + row0 + wm * 64 + tm * 16 + lq * 4;
    int bq2 = g / L;
    int l = g - bq2 * L;
#pragma unroll
    for (int r = 0; r < 4; ++r) {
      gl[tm][r] = l;
      if (++l == L) { l = 0; ++bq2; }
    }
  }
  __syncthreads();          // all frag reads of staging LDS complete
#pragma unroll
  for (int tn = 0; tn < 4; ++tn) {
    const int lc = wn * 64 + tn * 16 + lm;
    const int col = col0 + lc;
    const float bv = bias[col];
    float fr = 0.f, sgn = 0.f;
    if (epi == EPI_ROPE) {
      const int d0 = col % HD;
      fr = exp2f((float)(d0 % 56) * NEG_L2_10K_OVER_56);
      sgn = (d0 & 1) ? 1.f : -1.f;
    }
#pragma unroll
    for (int tm = 0; tm < 4; ++tm) {
#pragma unroll
      for (int r = 0; r < 4; ++r) {
        float v = acc[tm][tn][r] + bv;
        if (epi == EPI_ROPE) {
          const float prt = __shfl_xor(v, 1);   // partner col (lane^1), pre-rope
          float s, c;
          __sincosf((float)gl[tm][r] * fr, &s, &c);
          v = v * c + sgn * prt * s;
        }
        const int lr = wm * 64 + tm * 16 + lq * 4 + r;
        const int gp = (lc >> 3) ^ (((lr >> 2) & 3) << 1);
        Cs[lr * 128 + gp * 8 + (lc & 7)] = f2bf(v);
      }
    }
  }
  __syncthreads();
#pragma unroll
  for (int i = 0; i < 8; ++i) {
    const int ch = tid + 256 * i;
    const int lr = ch >> 4, g = ch & 15;
    const int phys = g ^ (((lr >> 2) & 3) << 1);
    const bf16x8_t val = *(const bf16x8_t*)&Cs[lr * 128 + phys * 8];
    const int grow = cfg.row_off + row0 + lr;
    const int bq2 = grow / L;
    const int l = grow - bq2 * L;
    const int col = col0 + g * 8;
    const int h = col / HD, d = col - h * HD;
    if (bq2 < BB)
      *(bf16x8_t*)&outB[((size_t)(bq2 * NH + h) * ltot + l) * HD + d] = val;
  }
}

// ======= pipelined AF32 GEMM (T- and S-group): depth-2 prefetch, counted vmcnt =======
// W: triple-buffered LDS via global_load_lds (issue k+2 at step k).
// A: f32->regs double-set (issue k+2 at step k; cvt + ds_write tile k+1 at step k).
// Per step: issue(k+2) -> s_waitcnt vmcnt(12) [tile k+1 complete, per-wave, BEFORE
// the barrier -> cross-wave safe] -> commit A(k+1) -> compute tile k -> lgkmcnt(0)
// -> raw s_barrier. Loads get a full step+ of latency budget; no vmcnt(0) drain.
struct ASet { float4 v[8]; };   // fixed-index only (rule #20)

__device__ __forceinline__ void a_issue(ASet& s, const float* Af, int row0,
                                        int k0, int tid)
{
#pragma unroll
  for (int j = 0; j < 4; ++j) {
    const int c = tid + 256 * j;
    const int row = c >> 3, g = c & 7;
    const float* p = Af + (size_t)(row0 + row) * DIM + k0 + g * 8;
    s.v[2 * j]     = *(const float4*)p;
    s.v[2 * j + 1] = *(const float4*)(p + 4);
  }
}
__device__ __forceinline__ void a_commit(const ASet& s, short* As, int tid)
{
#pragma unroll
  for (int j = 0; j < 4; ++j) {
    const int c = tid + 256 * j;
    const int row = c >> 3, g = c & 7;
    const float4 a0 = s.v[2 * j], a1 = s.v[2 * j + 1];
    uint4 w;
    w.x = cvt_pk_bf16(a0.x, a0.y); w.y = cvt_pk_bf16(a0.z, a0.w);
    w.z = cvt_pk_bf16(a1.x, a1.y); w.w = cvt_pk_bf16(a1.z, a1.w);
    *(uint4*)&As[row * 64 + ((g ^ (row & 7)) << 3)] = w;
  }
}
__device__ __forceinline__ void w_issue(const short* Wg, int k0, short* Wbuf,
                                        int wave, int lane)
{
#pragma unroll
  for (int j = 0; j < 4; ++j)
    gll16(Wg + (size_t)(j * 8) * DIM + k0, &Wbuf[(wave * 32 + j * 8) * 64], lane);
}

__global__ __launch_bounds__(256) void gemm_t(
    const float* __restrict__ Af, const short* __restrict__ Wt, EpiCfg cfg)
{
  __shared__ __align__(16) short lds[5 * 128 * 64];   // A0,A1,W0,W1,W2 = 80 KB
  short* ldsA = lds;
  short* ldsW = lds + 2 * 8192;
  const int tid = threadIdx.x;
  const int wave = tid >> 6, lane = tid & 63;

  int bx = blockIdx.x, by = blockIdx.y;
  if (cfg.swz) {
    const int nx = gridDim.x;
    const int bid = blockIdx.x + blockIdx.y * nx;   // HW dispatch order
    const int xcd = bid & 7, ixd = bid >> 3;
    const int rpx = gridDim.y >> 3;                 // row panels per XCD
    bx = ixd % nx;
    by = xcd * rpx + ixd / nx;
  }
  const int sub = bx / 7;
  const int col0 = (bx % 7) * 128;
  const int row0 = by * 128;
  const int wm = wave >> 1, wn = wave & 1;
  const int lm = lane & 15, lq = lane >> 4;

  // W staging base: lane -> row-in-8 = lane>>3, pre-swizzled source granule
  const int sr = lane >> 3;
  const int sg = (lane & 7) ^ sr;
  const short* Wg = Wt + (size_t)(sub * DIM + col0 + wave * 32 + sr) * DIM + sg * 8;

  f32x4_t acc[4][4];
#pragma unroll
  for (int i = 0; i < 4; ++i)
#pragma unroll
    for (int j = 0; j < 4; ++j) acc[i][j] = (f32x4_t){0.f, 0.f, 0.f, 0.f};

  ASet sA, sB;   // tiles: even -> sA, odd -> sB

  // prologue: issue tiles 0,1; commit tile 0
  w_issue(Wg, 0, ldsW, wave, lane);
  a_issue(sA, Af, row0, 0, tid);
  w_issue(Wg, 64, ldsW + 8192, wave, lane);
  a_issue(sB, Af, row0, 64, tid);
  asm volatile("s_waitcnt vmcnt(12)" ::: "memory");   // tile 0 done
  a_commit(sA, ldsA, tid);
  asm volatile("s_waitcnt lgkmcnt(0)" ::: "memory");
  __builtin_amdgcn_s_barrier();
  asm volatile("" ::: "memory");

#define TSTEP(k, Sissue, Scommit, VMS)                                         \
  {                                                                            \
    if ((k) + 2 < 14) {                                                        \
      w_issue(Wg, ((k) + 2) * 64, ldsW + (((k) + 2) % 3) * 8192, wave, lane);  \
      a_issue(Sissue, Af, row0, ((k) + 2) * 64, tid);                          \
    }                                                                          \
    asm volatile("s_waitcnt " VMS ::: "memory");                               \
    if ((k) + 1 < 14)                                                          \
      a_commit(Scommit, ldsA + (((k) + 1) & 1) * 8192, tid);                   \
    compute_step(ldsA + ((k) & 1) * 8192, ldsW + ((k) % 3) * 8192,             \
                 acc, wm, wn, lm, lq);                                         \
    asm volatile("s_waitcnt lgkmcnt(0)" ::: "memory");                         \
    __builtin_amdgcn_s_barrier();                                              \
    asm volatile("" ::: "memory");                                             \
  }

  TSTEP(0,  sA, sB, "vmcnt(12)")
  TSTEP(1,  sB, sA, "vmcnt(12)")
  TSTEP(2,  sA, sB, "vmcnt(12)")
  TSTEP(3,  sB, sA, "vmcnt(12)")
  TSTEP(4,  sA, sB, "vmcnt(12)")
  TSTEP(5,  sB, sA, "vmcnt(12)")
  TSTEP(6,  sA, sB, "vmcnt(12)")
  TSTEP(7,  sB, sA, "vmcnt(12)")
  TSTEP(8,  sA, sB, "vmcnt(12)")
  TSTEP(9,  sB, sA, "vmcnt(12)")
  TSTEP(10, sA, sB, "vmcnt(12)")
  TSTEP(11, sB, sA, "vmcnt(12)")
  TSTEP(12, sA, sB, "vmcnt(0)")
  TSTEP(13, sB, sA, "vmcnt(0)")
#undef TSTEP

  epilogue_hm(lds, acc, cfg, bx, by, wm, wn, lm, lq, tid);
}

// ---------------- r9-proven 1-phase GEMM body (bf16-A and FFN paths) ----------------
template <bool AF32, bool DOLN>
__device__ __forceinline__ void gemm_body(
    short* As, short* Bs,
    const short* A, const float* Af, const short* Wt,
    const EpiCfg& cfg, int bx, int by,
    const float* smu, const float* srs,
    const float* lngam, const float* lnbet)
{
  const int tid = threadIdx.x;
  const int wave = tid >> 6, lane = tid & 63;
  const int sub = bx / 7;
  const int col0 = (bx % 7) * 128;
  const int row0 = by * 128;
  const int wm = wave >> 1, wn = wave & 1;
  const int lm = lane & 15, lq = lane >> 4;

  const int sr = lane >> 3;
  const int sg = (lane & 7) ^ sr;          // pre-swizzled source granule
  const short* Wg = Wt + (size_t)(sub * DIM + col0 + wave * 32 + sr) * DIM + sg * 8;
  const short* Ag = nullptr;
  if constexpr (!AF32)
    Ag = A + (size_t)(row0 + wave * 32 + sr) * DIM + sg * 8;

  f32x4_t acc[4][4];
#pragma unroll
  for (int i = 0; i < 4; ++i)
#pragma unroll
    for (int j = 0; j < 4; ++j) acc[i][j] = (f32x4_t){0.f, 0.f, 0.f, 0.f};

  for (int k0 = 0; k0 < DIM; k0 += 64) {
    __syncthreads();
    if constexpr (AF32) {
#pragma unroll
      for (int j = 0; j < 4; ++j) {
        const int c = tid + 256 * j;
        const int row = c >> 3, g = c & 7;
        const float* srcp = Af + (size_t)(row0 + row) * DIM + k0 + g * 8;
        const float4 a0 = *(const float4*)srcp;
        const float4 a1 = *(const float4*)(srcp + 4);
        float e[8] = {a0.x, a0.y, a0.z, a0.w, a1.x, a1.y, a1.z, a1.w};
        if constexpr (DOLN) {
          const float mu = smu[row], rs = srs[row];
#pragma unroll
          for (int q = 0; q < 8; ++q) {
            const int k = k0 + g * 8 + q;
            e[q] = (e[q] - mu) * rs * lngam[k] + lnbet[k];
          }
        }
        uint4 w;
        w.x = cvt_pk_bf16(e[0], e[1]); w.y = cvt_pk_bf16(e[2], e[3]);
        w.z = cvt_pk_bf16(e[4], e[5]); w.w = cvt_pk_bf16(e[6], e[7]);
        *(uint4*)&As[row * 64 + ((g ^ (row & 7)) << 3)] = w;
      }
    } else {
#pragma unroll
      for (int j = 0; j < 4; ++j)
        gll16(Ag + (size_t)(j * 8) * DIM + k0, &As[(wave * 32 + j * 8) * 64], lane);
    }
#pragma unroll
    for (int j = 0; j < 4; ++j)
      gll16(Wg + (size_t)(j * 8) * DIM + k0, &Bs[(wave * 32 + j * 8) * 64], lane);
    __syncthreads();

    compute_step(As, Bs, acc, wm, wn, lm, lq);
  }

  const int hm = cfg.hm[sub];
  if (hm) {
    epilogue_hm(As, acc, cfg, bx, by, wm, wn, lm, lq, tid);
    return;
  }

  // non-hm path (outF f32: out-proj RESID, FFN RELU)
  const float* bias = cfg.bias[sub];
  float* outF = cfg.outF[sub];
  short* outB = cfg.outB[sub];
  const int epi = cfg.epi[sub];
#pragma unroll
  for (int tn = 0; tn < 4; ++tn) {
    const int col = col0 + wn * 64 + tn * 16 + lm;
    const float bv = bias[col];
#pragma unroll
    for (int tm = 0; tm < 4; ++tm) {
#pragma unroll
      for (int r = 0; r < 4; ++r) {
        const int grow = cfg.row_off + row0 + wm * 64 + tm * 16 + lq * 4 + r;
        float v = acc[tm][tn][r] + bv;
        if (epi == EPI_RESID) {
          v += cfg.resid[(size_t)grow * DIM + col];
        } else if (epi == EPI_RELU) {
          v = fmaxf(v, 0.f);
        }
        if (outB) outB[(size_t)grow * DIM + col] = f2bf(v);
        else      outF[(size_t)grow * DIM + col] = v;
      }
    }
  }
}

__global__ __launch_bounds__(256) void gemm_bf16(
    const short* __restrict__ A, const short* __restrict__ Wt, EpiCfg cfg)
{
  __shared__ __align__(16) short lds[2 * 128 * 64];
  gemm_body<false, false>(lds, lds + 128 * 64, A, nullptr, Wt, cfg,
                          blockIdx.x, blockIdx.y, nullptr, nullptr, nullptr, nullptr);
}

// FFN GEMM with fused LayerNorm on the A-staging (A = LN(y); K range == LN row).
__global__ __launch_bounds__(256) void gemm_ffn(
    const float* __restrict__ Y, const float* __restrict__ lng,
    const float* __restrict__ lnb, const short* __restrict__ Wt, EpiCfg cfg)
{
  __shared__ __align__(16) short lds[2 * 128 * 64];
  __shared__ float glds[DIM], blds[DIM];
  __shared__ float smu[128], srs[128];
  const int tid = threadIdx.x;
  const int row0 = blockIdx.y * 128;
  for (int i = tid; i < DIM; i += 256) { glds[i] = lng[i]; blds[i] = lnb[i]; }
  {
    const int r = tid >> 1, h = tid & 1;   // 2 threads per row, 448 elems each
    const float* rp = Y + (size_t)(row0 + r) * DIM + h * 448;
    float s = 0.f, q = 0.f;
    for (int i = 0; i < 448; i += 4) {
      const float4 v = *(const float4*)(rp + i);
      s += v.x + v.y + v.z + v.w;
      q = fmaf(v.x, v.x, fmaf(v.y, v.y, fmaf(v.z, v.z, fmaf(v.w, v.w, q))));
    }
    s += __shfl_xor(s, 1);
    q += __shfl_xor(q, 1);
    if (h == 0) {
      const float mu = s * (1.f / DIM);
      const float var = q * (1.f / DIM) - mu * mu;
      smu[r] = mu;
      srs[r] = 1.f / sqrtf(var + 1e-5f);
    }
  }
  __syncthreads();
  gemm_body<true, true>(lds, lds + 128 * 64, nullptr, Y, Wt, cfg,
                        blockIdx.x, blockIdx.y, smu, srs, glds, blds);
}

// ---------------- attention: one 1024-thread block per (b,h) (round-1 proven) -------
#define SCP 10   // score row stride (floats): conflict-free (gcd(10,32)=2), float2-aligned

__global__ __launch_bounds__(1024, 8) void attn_kernel(
    const short* __restrict__ q, const short* __restrict__ kall,
    const short* __restrict__ vall, const float* __restrict__ gate,
    short* __restrict__ out)
{
  __shared__ __align__(16) float qs[TT * HD];        // 3584 B
  __shared__ __align__(16) float sc[NKEYS * SCP];    // 23400 B, [k][t] padded
  __shared__ float red[TT * TT * HD];                // 28672 B, [g][t][d]
  __shared__ float isum[TT];
  const int tid = threadIdx.x;
  const int bh = blockIdx.x;
  const float scale = 0.09449111825230681f;  // 1/sqrt(112)
  const float rg = tanhf(gate[0]);

  // phase 0: q -> fp32 LDS (contiguous head-major load)
  if (tid < TT * HD) qs[tid] = bf2f(q[(size_t)bh * (TT * HD) + tid]);
  __syncthreads();

  // phase 1: scores — one thread per key, contiguous 224 B key row
  if (tid < NKEYS) {
    const int k = tid;
    const short* kp = kall + ((size_t)bh * NKEYS + k) * HD;
    float dot[TT] = {};
    for (int d8 = 0; d8 < HD; d8 += 8) {
      const bf16x8_t kv8 = *(const bf16x8_t*)(kp + d8);
      float kf[8];
#pragma unroll
      for (int j = 0; j < 8; ++j) kf[j] = bf2f(kv8[j]);
#pragma unroll
      for (int t = 0; t < TT; ++t) {
        const float4 qa = *(const float4*)&qs[t * HD + d8];
        const float4 qb4 = *(const float4*)&qs[t * HD + d8 + 4];
        dot[t] = fmaf(qa.x, kf[0], dot[t]);
        dot[t] = fmaf(qa.y, kf[1], dot[t]);
        dot[t] = fmaf(qa.z, kf[2], dot[t]);
        dot[t] = fmaf(qa.w, kf[3], dot[t]);
        dot[t] = fmaf(qb4.x, kf[4], dot[t]);
        dot[t] = fmaf(qb4.y, kf[5], dot[t]);
        dot[t] = fmaf(qb4.z, kf[6], dot[t]);
        dot[t] = fmaf(qb4.w, kf[7], dot[t]);
      }
    }
    const float s = (k >= TT + KA) ? scale * rg : scale;
#pragma unroll
    for (int t = 0; t < TT; ++t) sc[k * SCP + t] = dot[t] * s;
  }
  __syncthreads();

  // phase 2: softmax per t-row, one wave per row
  const int wave = tid >> 6, lane = tid & 63;
  if (wave < TT) {
    const int t = wave;
    float m = -1e30f;
    for (int k = lane; k < NKEYS; k += 64) m = fmaxf(m, sc[k * SCP + t]);
#pragma unroll
    for (int o = 32; o >= 1; o >>= 1) m = fmaxf(m, __shfl_xor(m, o));
    float sum = 0.f;
    for (int k = lane; k < NKEYS; k += 64) {
      const float e = expf(sc[k * SCP + t] - m);
      sc[k * SCP + t] = e;
      sum += e;
    }
#pragma unroll
    for (int o = 32; o >= 1; o >>= 1) sum += __shfl_xor(sum, o);
    if (lane == 0) isum[t] = 1.f / sum;
  }
  __syncthreads();

  // phase 3: PV partials — keys split 8 ways, each thread owns (group g, dim d)
  if (tid < TT * HD) {
    const int g = tid / HD, d = tid - (tid / HD) * HD;
    const int kb = (g * NKEYS) / TT, ke = ((g + 1) * NKEYS) / TT;
    const short* vp = vall + (size_t)bh * (NKEYS * HD) + d;
    float acc[TT] = {};
    for (int k = kb; k < ke; ++k) {
      const float vv = bf2f(vp[(size_t)k * HD]);
      const float2 s0 = *(const float2*)&sc[k * SCP];
      const float2 s1 = *(const float2*)&sc[k * SCP + 2];
      const float2 s2 = *(const float2*)&sc[k * SCP + 4];
      const float2 s3 = *(const float2*)&sc[k * SCP + 6];
      acc[0] = fmaf(s0.x, vv, acc[0]);
      acc[1] = fmaf(s0.y, vv, acc[1]);
      acc[2] = fmaf(s1.x, vv, acc[2]);
      acc[3] = fmaf(s1.y, vv, acc[3]);
      acc[4] = fmaf(s2.x, vv, acc[4]);
      acc[5] = fmaf(s2.y, vv, acc[5]);
      acc[6] = fmaf(s3.x, vv, acc[6]);
      acc[7] = fmaf(s3.y, vv, acc[7]);
    }
#pragma unroll
    for (int t = 0; t < TT; ++t) red[(g * TT + t) * HD + d] = acc[t];
  }
  __syncthreads();

  // phase 4: cross-group reduce + normalize + store (row-major for out-proj)
  if (tid < TT * HD) {
    const int t = tid / HD, d = tid - (tid / HD) * HD;
    float a = 0.f;
#pragma unroll
    for (int g = 0; g < TT; ++g) a += red[(g * TT + t) * HD + d];
    out[((size_t)(bh >> 3) * TT + t) * DIM + (bh & 7) * HD + d] = f2bf(a * isum[t]);
  }
}

// ---------------- launch ----------------
extern "C" void kernel_launch(void* const* d_in, const int* in_sizes, int n_in,
                              void* d_out, int out_size, void* d_ws, size_t ws_size,
                              hipStream_t stream)
{
  const float* x   = (const float*)d_in[0];
  const float* h_a = (const float*)d_in[1];
  const float* h_t = (const float*)d_in[2];
  const float* p   = (const float*)d_in[3];
  const float* Wq  = (const float*)d_in[4];  const float* bq  = (const float*)d_in[5];
  const float* Wks = (const float*)d_in[6];  const float* bks = (const float*)d_in[7];
  const float* Wvs = (const float*)d_in[8];  const float* bvs = (const float*)d_in[9];
  const float* Wka = (const float*)d_in[10]; const float* bka = (const float*)d_in[11];
  const float* Wva = (const float*)d_in[12]; const float* bva = (const float*)d_in[13];
  const float* Wkt = (const float*)d_in[14]; const float* bkt = (const float*)d_in[15];
  const float* Wvt = (const float*)d_in[16]; const float* bvt = (const float*)d_in[17];
  const float* Wo  = (const float*)d_in[18]; const float* bo  = (const float*)d_in[19];
  const float* Wf  = (const float*)d_in[20]; const float* bf_ = (const float*)d_in[21];
  const float* gate = (const float*)d_in[22];
  const float* ln_g = (const float*)d_in[23];
  const float* ln_b = (const float*)d_in[24];

  // ---- workspace layout (bytes) ----
  const size_t SZ_HAD = (size_t)KAPAD * DIM * 2;            // bf16
  const size_t SZ_SM  = (size_t)BB * TT * DIM * 2;          // bf16 small [512 x 896]
  const size_t SZ_KV  = (size_t)BB * NH * NKEYS * HD * 2;   // bf16 [b][h][585][112]
  const size_t SZ_WT  = (size_t)9 * DD * 2;                 // 9 weights bf16
  const size_t needed = SZ_HAD + SZ_SM * 2 + SZ_KV * 2 + SZ_WT
                        + (size_t)BB * TT * DIM * 4;        // + yb fp32
  if (ws_size < needed) return;  // fail loud, not UB

  char* wsp = (char*)d_ws;
  short* hadb = (short*)wsp; wsp += SZ_HAD;
  short* qb   = (short*)wsp; wsp += SZ_SM;   // head-major [b][h][8][112]
  short* kall = (short*)wsp; wsp += SZ_KV;   // head-major [b][h][585][112]
  short* vall = (short*)wsp; wsp += SZ_KV;
  short* WtA  = (short*)wsp; wsp += SZ_WT;
  short* attn_outb = (short*)wsp; wsp += SZ_SM;
  float* yb   = (float*)wsp; wsp += (size_t)BB * TT * DIM * 4;

  dim3 blk(256);

  // 0) transpose all 9 weights -> bf16 [n][k], concatenated
  W9 w9; const float* Ws[9] = {Wq, Wks, Wvs, Wka, Wva, Wkt, Wvt, Wo, Wf};
  for (int i = 0; i < 9; ++i) w9.w[i] = Ws[i];
  wtrans<<<dim3(28, 28, 9), blk, 0, stream>>>(w9, WtA);

  // 1) h_ad -> bf16
  build_had<<<(KAPAD * DIM / 8 + 255) / 256, blk, 0, stream>>>(h_a, p, hadb);

  // 2) fused S-group GEMM (pipelined): [q | k_s | v_s] = x(f32) @ [Wq|Wks|Wvs]
  {
    EpiCfg c = {};
    c.bias[0] = bq;  c.outB[0] = qb;   c.epi[0] = EPI_ROPE; c.pos_mod[0] = TT;
    c.hm[0] = 1; c.hm_L[0] = TT; c.hm_ltot[0] = TT;
    c.bias[1] = bks; c.outB[1] = kall; c.epi[1] = EPI_ROPE; c.pos_mod[1] = TT;
    c.hm[1] = 1; c.hm_L[1] = TT; c.hm_ltot[1] = NKEYS;
    c.bias[2] = bvs; c.outB[2] = vall; c.epi[2] = EPI_NONE; c.pos_mod[2] = 1;
    c.hm[2] = 1; c.hm_L[2] = TT; c.hm_ltot[2] = NKEYS;
    gemm_t<<<dim3(21, BB * TT / 128), blk, 0, stream>>>(x, WtA, c);
  }
  // 3) fused A-group GEMM: [k_a | v_a] = hadb @ [Wka|Wva] (head-major, seg off 8)
  {
    EpiCfg c = {};
    c.bias[0] = bka; c.outB[0] = kall + (size_t)TT * HD; c.epi[0] = EPI_ROPE;
    c.pos_mod[0] = KA; c.hm[0] = 1; c.hm_L[0] = KA; c.hm_ltot[0] = NKEYS;
    c.bias[1] = bva; c.outB[1] = vall + (size_t)TT * HD; c.epi[1] = EPI_NONE;
    c.pos_mod[1] = 1; c.hm[1] = 1; c.hm_L[1] = KA; c.hm_ltot[1] = NKEYS;
    gemm_bf16<<<dim3(14, KAPAD / 128), blk, 0, stream>>>(
        hadb, WtA + (size_t)3 * DD, c);
  }
  // 4) T-group GEMM (pipelined), XCD-swizzled (gridDim.y=256, %8==0)
  {
    EpiCfg c = {};
    c.bias[0] = bkt; c.outB[0] = kall + (size_t)(TT + KA) * HD; c.epi[0] = EPI_ROPE;
    c.pos_mod[0] = KT; c.hm[0] = 1; c.hm_L[0] = KT; c.hm_ltot[0] = NKEYS;
    c.bias[1] = bvt; c.outB[1] = vall + (size_t)(TT + KA) * HD; c.epi[1] = EPI_NONE;
    c.pos_mod[1] = 1; c.hm[1] = 1; c.hm_L[1] = KT; c.hm_ltot[1] = NKEYS;
    c.row_off = 0;
    c.swz = 1;
    gemm_t<<<dim3(14, BB * KT / 128), blk, 0, stream>>>(
        h_t, WtA + (size_t)5 * DD, c);
  }

  // 5) attention — proven kernel, 1024 threads/block
  attn_kernel<<<BB * NH, dim3(1024), 0, stream>>>(qb, kall, vall, gate, attn_outb);

  // 6) out-proj + residual (fp32 out)
  {
    EpiCfg c = {};
    c.bias[0] = bo; c.outF[0] = yb; c.epi[0] = EPI_RESID; c.pos_mod[0] = 1;
    c.resid = x;
    gemm_bf16<<<dim3(7, BB * TT / 128), blk, 0, stream>>>(
        attn_outb, WtA + (size_t)7 * DD, c);
  }
  // 7) FFN with fused LayerNorm + ReLU (fp32 d_out)
  {
    EpiCfg c = {};
    c.bias[0] = bf_; c.outF[0] = (float*)d_out; c.epi[0] = EPI_RELU; c.pos_mod[0] = 1;
    gemm_ffn<<<dim3(7, BB * TT / 128), blk, 0, stream>>>(
        yb, ln_g, ln_b, WtA + (size_t)8 * DD, c);
  }
}